// Round 6
// baseline (367.358 us; speedup 1.0000x reference)
//
#include <hip/hip_runtime.h>

static constexpr int NN = 50000;
static constexpr int NE = 800000;
static constexpr int NB = (NN + 255) / 256;  // 196 scan blocks
static constexpr float DSCALE = 33554432.f;  // 2^25 fixed-point for degree

typedef __attribute__((ext_vector_type(8))) short bf16x8;
typedef __attribute__((ext_vector_type(4))) float f32x4;

__device__ __forceinline__ unsigned short f2bf(float f) {  // RNE
  unsigned u = __float_as_uint(f);
  u += 0x7fffu + ((u >> 16) & 1u);
  return (unsigned short)(u >> 16);
}
__device__ __forceinline__ float bf_lo(unsigned v) { return __uint_as_float(v << 16); }
__device__ __forceinline__ float bf_hi(unsigned v) { return __uint_as_float(v & 0xffff0000u); }

__device__ __forceinline__ void bf8_unpack(uint4 v, float* f) {
  f[0] = bf_lo(v.x); f[1] = bf_hi(v.x); f[2] = bf_lo(v.y); f[3] = bf_hi(v.y);
  f[4] = bf_lo(v.z); f[5] = bf_hi(v.z); f[6] = bf_lo(v.w); f[7] = bf_hi(v.w);
}
__device__ __forceinline__ uint4 bf8_pack(const float* f) {
  uint4 o;
  o.x = (unsigned)f2bf(f[0]) | ((unsigned)f2bf(f[1]) << 16);
  o.y = (unsigned)f2bf(f[2]) | ((unsigned)f2bf(f[3]) << 16);
  o.z = (unsigned)f2bf(f[4]) | ((unsigned)f2bf(f[5]) << 16);
  o.w = (unsigned)f2bf(f[6]) | ((unsigned)f2bf(f[7]) << 16);
  return o;
}

// ---- init packed degree/count: deg=1.0 (self-loop), cnt=0 ----
__global__ void k_init(unsigned long long* __restrict__ packed) {
  int i = blockIdx.x * 256 + threadIdx.x;
  if (i < NN) packed[i] = ((unsigned long long)(unsigned)DSCALE) << 32;
}

// ---- per-edge: ONE 64-bit atomic = fixed-point weight (hi) + count (lo) ----
__global__ void k_deg_hist(const int* __restrict__ col, const float* __restrict__ w,
                           unsigned long long* __restrict__ packed) {
  int e = blockIdx.x * 256 + threadIdx.x;
  if (e < NE) {
    unsigned fx = (unsigned)(w[e] * DSCALE + 0.5f);
    atomicAdd(&packed[col[e]], (((unsigned long long)fx) << 32) | 1ull);
  }
}

// ---- scan part (block-reduce counts) + dinv, fused ----
__global__ __launch_bounds__(256) void k_scan_part(const unsigned long long* __restrict__ packed,
                                                   int* __restrict__ partial,
                                                   float* __restrict__ dinv) {
  __shared__ int s[256];
  int t = threadIdx.x;
  int i = blockIdx.x * 256 + t;
  unsigned long long pk = (i < NN) ? packed[i] : 0ull;
  if (i < NN) dinv[i] = rsqrtf((float)(pk >> 32) * (1.0f / DSCALE));
  s[t] = (i < NN) ? (int)(pk & 0xffffffffu) : 0;
  __syncthreads();
  for (int off = 128; off > 0; off >>= 1) {
    if (t < off) s[t] += s[t + off];
    __syncthreads();
  }
  if (t == 0) partial[blockIdx.x] = s[0];
}

__global__ void k_scan_base(const int* __restrict__ partial, int* __restrict__ base,
                            int* __restrict__ rowptr) {
  __shared__ int s[256];
  int t = threadIdx.x;
  s[t] = (t < NB) ? partial[t] : 0;
  __syncthreads();
  if (t == 0) {
    int run = 0;
    for (int i = 0; i < NB; ++i) { int v = s[i]; s[i] = run; run += v; }
    rowptr[NN] = run;  // == NE
  }
  __syncthreads();
  if (t < NB) base[t] = s[t];
}

__global__ __launch_bounds__(256) void k_scan_final(const unsigned long long* __restrict__ packed,
                                                    const int* __restrict__ base,
                                                    int* __restrict__ rowptr,
                                                    int* __restrict__ wcur) {
  __shared__ int s[256];
  int t = threadIdx.x;
  int i = blockIdx.x * 256 + t;
  int v = (i < NN) ? (int)(packed[i] & 0xffffffffu) : 0;
  s[t] = v;
  __syncthreads();
#pragma unroll
  for (int off = 1; off < 256; off <<= 1) {
    int a = (t >= off) ? s[t - off] : 0;
    __syncthreads();
    s[t] += a;
    __syncthreads();
  }
  int excl = s[t] - v + base[blockIdx.x];
  if (i < NN) { rowptr[i] = excl; wcur[i] = excl; }
}

// ---- fill CSR: packed (src, nrm) records sorted by target ----
__global__ void k_fill(const int* __restrict__ row, const int* __restrict__ col,
                       const float* __restrict__ w, const float* __restrict__ dinv,
                       int* __restrict__ wcur, int2* __restrict__ rec) {
  int e = blockIdx.x * 256 + threadIdx.x;
  if (e >= NE) return;
  int r = row[e], c = col[e];
  int pos = atomicAdd(&wcur[c], 1);
  rec[pos] = make_int2(r, __float_as_int(dinv[r] * w[e] * dinv[c]));
}

// ---- cast fp32 -> bf16, 4 at a time ----
__global__ void k_cast(const float* __restrict__ src, unsigned short* __restrict__ dst, int n4) {
  int i = blockIdx.x * 256 + threadIdx.x;
  if (i >= n4) return;
  float4 v = reinterpret_cast<const float4*>(src)[i];
  uint2 o;
  o.x = (unsigned)f2bf(v.x) | ((unsigned)f2bf(v.y) << 16);
  o.y = (unsigned)f2bf(v.z) | ((unsigned)f2bf(v.w) << 16);
  reinterpret_cast<uint2*>(dst)[i] = o;
}

// ---- propagate half-pass (bf16 h, fp32 accum, 16B chunks).
// MODE 0: outb=prop; 1: outb=add+prop; 2: outf+=prop. colbase selects column half.
template<int F, int MODE>
__global__ __launch_bounds__(256) void k_gatherb(const unsigned short* __restrict__ h,
                                                 const float* __restrict__ dinv,
                                                 const int* __restrict__ rowptr,
                                                 const int2* __restrict__ rec,
                                                 const unsigned short* __restrict__ add,
                                                 unsigned short* __restrict__ outb,
                                                 float* __restrict__ outf,
                                                 int colbase) {
  constexpr int CH = F / 16;  // 16B chunks per half-pass (half the row)
  int idx = blockIdx.x * 256 + threadIdx.x;
  if (idx >= NN * CH) return;
  int node = idx / CH;
  int col = colbase + (idx - node * CH) * 8;
  const size_t base = (size_t)node * F + col;
  uint4 hv = *reinterpret_cast<const uint4*>(h + base);
  float hx[8]; bf8_unpack(hv, hx);
  float di = dinv[node];
  float d2 = di * di;
  float a[8];
#pragma unroll
  for (int j = 0; j < 8; ++j) a[j] = d2 * hx[j];
  if (MODE == 1) {
    uint4 av = *reinterpret_cast<const uint4*>(add + base);
    float ax[8]; bf8_unpack(av, ax);
#pragma unroll
    for (int j = 0; j < 8; ++j) a[j] += ax[j];
  } else if (MODE == 2) {
    float4 o0 = *reinterpret_cast<const float4*>(outf + base);
    float4 o1 = *reinterpret_cast<const float4*>(outf + base + 4);
    a[0] += o0.x; a[1] += o0.y; a[2] += o0.z; a[3] += o0.w;
    a[4] += o1.x; a[5] += o1.y; a[6] += o1.z; a[7] += o1.w;
  }
  int e0 = rowptr[node], e1 = rowptr[node + 1];
  for (int e = e0; e < e1; ++e) {
    int2 rv = rec[e];
    float nm = __int_as_float(rv.y);
    uint4 sv = *reinterpret_cast<const uint4*>(h + (size_t)rv.x * F + col);
    float sx[8]; bf8_unpack(sv, sx);
#pragma unroll
    for (int j = 0; j < 8; ++j) a[j] += nm * sx[j];
  }
  if (MODE == 2) {
    *reinterpret_cast<float4*>(outf + base) = make_float4(a[0], a[1], a[2], a[3]);
    *reinterpret_cast<float4*>(outf + base + 4) = make_float4(a[4], a[5], a[6], a[7]);
  } else {
    *reinterpret_cast<uint4*>(outb + base) = bf8_pack(a);
  }
}

// ---- B-fragment packing helper (16x16x32 MFMA B layout) ----
__device__ __forceinline__ void bfrag_item(const float* __restrict__ W,
                                           unsigned short* __restrict__ Bf,
                                           int K, int idx) {
  int fragc = (K / 32) * 4 * 64;
  int mat = idx / fragc;
  int rem = idx - mat * fragc;
  int lane = rem & 63;
  int nt = (rem >> 6) & 3;
  int kt = rem >> 8;
  int lrow = lane & 15, lgrp = lane >> 4;
  const float* Wm = W + (size_t)mat * K * 64;
  float o[8];
#pragma unroll
  for (int j = 0; j < 8; ++j)
    o[j] = Wm[(size_t)(kt * 32 + lgrp * 8 + j) * 64 + nt * 16 + lrow];
  *reinterpret_cast<uint4*>(Bf + (size_t)idx * 8) = bf8_pack(o);
}

// ---- merged weight prep: Wc (blocks 0..143), bc (block 144), BfW1 (blocks 145..153) ----
__global__ __launch_bounds__(256) void k_prep(const float* __restrict__ W1,
                                              const float* __restrict__ W2,
                                              const float* __restrict__ Wlin,
                                              const float* __restrict__ b2,
                                              const float* __restrict__ bl,
                                              float* __restrict__ Wc,
                                              float* __restrict__ bc,
                                              unsigned short* __restrict__ BfW1) {
  int b = blockIdx.x;
  int t = threadIdx.x;
  if (b < 144) {  // Wc[p] = W2[p] @ Wl[64p:64p+64,:]  (3*192*64 = 36864)
    int idx = b * 256 + t;
    int j = idx & 63;
    int k = (idx >> 6) % 192;
    int p = idx / (192 * 64);
    float s = 0.f;
    for (int m = 0; m < 64; ++m)
      s += W2[(p * 192 + k) * 64 + m] * Wlin[(p * 64 + m) * 64 + j];
    Wc[idx] = s;
  } else if (b == 144) {
    if (t < 64) {
      float s = bl[t];
      for (int p = 0; p < 3; ++p)
        for (int m = 0; m < 64; ++m)
          s += b2[p * 64 + m] * Wlin[(p * 64 + m) * 64 + t];
      bc[t] = s;
    }
  } else {  // BfW1: 3 mats * 768 frags
    int idx = (b - 145) * 256 + t;
    if (idx < 3 * 768) bfrag_item(W1, BfW1, 96, idx);
  }
}

__global__ void k_bfragWc(const float* __restrict__ Wc, unsigned short* __restrict__ BfWc) {
  int idx = blockIdx.x * 256 + threadIdx.x;
  if (idx < 3 * 1536) bfrag_item(Wc, BfWc, 192, idx);
}

// ---- MFMA GEMM: [NN x K](bf16) @ [K x 64] -> 16-row tile per wave, no LDS ----
// MODE 0: bf16 out, +bias, ReLU; MODE 1: bf16 out; MODE 2: fp32 out, +bias
template<int K, int MODE>
__global__ __launch_bounds__(256) void k_mgemm(const unsigned short* __restrict__ A,
                                               const unsigned short* __restrict__ Bf,
                                               const float* __restrict__ bias,
                                               unsigned short* __restrict__ Cb,
                                               float* __restrict__ Cf,
                                               int ldc, int coff) {
  constexpr int KT = K / 32;
  int lane = threadIdx.x & 63;
  int wave = blockIdx.x * 4 + (threadIdx.x >> 6);
  int r0 = wave * 16;
  if (r0 >= NN) return;
  int lrow = lane & 15, lgrp = lane >> 4;
  const unsigned short* ap = A + (size_t)(r0 + lrow) * K + lgrp * 8;
  f32x4 acc[4];
#pragma unroll
  for (int nt = 0; nt < 4; ++nt) acc[nt] = (f32x4){0.f, 0.f, 0.f, 0.f};
#pragma unroll
  for (int kt = 0; kt < KT; ++kt) {
    bf16x8 af = *reinterpret_cast<const bf16x8*>(ap + kt * 32);
#pragma unroll
    for (int nt = 0; nt < 4; ++nt) {
      bf16x8 bfr = *reinterpret_cast<const bf16x8*>(Bf + (size_t)((kt * 4 + nt) * 64 + lane) * 8);
      acc[nt] = __builtin_amdgcn_mfma_f32_16x16x32_bf16(af, bfr, acc[nt], 0, 0, 0);
    }
  }
#pragma unroll
  for (int nt = 0; nt < 4; ++nt) {
#pragma unroll
    for (int reg = 0; reg < 4; ++reg) {
      int rr = r0 + lgrp * 4 + reg;
      int cc = coff + nt * 16 + lrow;
      float v = acc[nt][reg];
      if (MODE != 1) v += bias[nt * 16 + lrow];
      if (MODE == 0) v = fmaxf(v, 0.f);
      if (MODE == 2) Cf[(size_t)rr * ldc + cc] = v;
      else           Cb[(size_t)rr * ldc + cc] = f2bf(v);
    }
  }
}

extern "C" void kernel_launch(void* const* d_in, const int* in_sizes, int n_in,
                              void* d_out, int out_size, void* d_ws, size_t ws_size,
                              hipStream_t stream) {
  const float* x    = (const float*)d_in[0];
  const int*   ei   = (const int*)d_in[1];
  const float* ew   = (const float*)d_in[2];
  const float* W1   = (const float*)d_in[3];
  const float* b1   = (const float*)d_in[4];
  const float* W2   = (const float*)d_in[5];
  const float* b2   = (const float*)d_in[6];
  const float* Wlin = (const float*)d_in[7];
  const float* bl   = (const float*)d_in[8];
  float* out = (float*)d_out;

  const int* row = ei;
  const int* col = ei + NE;

  char* wsb = (char*)d_ws;
  unsigned long long* packed = (unsigned long long*)wsb; wsb += NN * 8;
  float* dinv    = (float*)wsb;  wsb += NN * 4;
  int*   rowptr  = (int*)wsb;    wsb += (NN + 1) * 4;
  int*   wcur    = (int*)wsb;    wsb += NN * 4;
  int*   partial = (int*)wsb;    wsb += 256 * 4;
  int*   sbase   = (int*)wsb;    wsb += 256 * 4;
  wsb = (char*)(((size_t)wsb + 15) & ~(size_t)15);
  int2*  rec     = (int2*)wsb;   wsb += (size_t)NE * 8;
  float* Wc      = (float*)wsb;  wsb += 3 * 192 * 64 * 4;
  float* bc      = (float*)wsb;  wsb += 64 * 4;
  wsb = (char*)(((size_t)wsb + 15) & ~(size_t)15);
  unsigned short* BfW1 = (unsigned short*)wsb; wsb += (size_t)3 * 768 * 8 * 2;   // K=96 frags
  unsigned short* BfWc = (unsigned short*)wsb; wsb += (size_t)3 * 1536 * 8 * 2;  // K=192 frags
  wsb = (char*)(((size_t)wsb + 15) & ~(size_t)15);
  unsigned short* xb   = (unsigned short*)wsb; wsb += (size_t)NN * 96 * 2;
  unsigned short* c1   = (unsigned short*)wsb; wsb += (size_t)NN * 192 * 2;
  unsigned short* bufB = (unsigned short*)wsb;  // p1|p2 (2*96) then z1|z2|sB (3*64)
  unsigned short* p1 = bufB;
  unsigned short* p2 = bufB + (size_t)NN * 96;
  unsigned short* z1 = bufB;
  unsigned short* z2 = bufB + (size_t)NN * 64;
  unsigned short* sB = bufB + (size_t)NN * 128;

  auto cdiv = [](long long a, long long b) { return (int)((a + b - 1) / b); };

  // gcn_norm + CSR build
  k_init<<<cdiv(NN, 256), 256, 0, stream>>>(packed);
  k_deg_hist<<<cdiv(NE, 256), 256, 0, stream>>>(col, ew, packed);
  k_scan_part<<<NB, 256, 0, stream>>>(packed, partial, dinv);
  k_scan_base<<<1, 256, 0, stream>>>(partial, sbase, rowptr);
  k_scan_final<<<NB, 256, 0, stream>>>(packed, sbase, rowptr, wcur);
  k_fill<<<cdiv(NE, 256), 256, 0, stream>>>(row, col, ew, dinv, wcur, rec);

  // weight prep (Wc, bc, BfW1 merged), then BfWc (needs Wc), x cast
  k_prep<<<154, 256, 0, stream>>>(W1, W2, Wlin, b2, bl, Wc, bc, BfW1);
  k_bfragWc<<<cdiv(3 * 1536, 256), 256, 0, stream>>>(Wc, BfWc);
  k_cast<<<cdiv(NN * 24, 256), 256, 0, stream>>>(x, xb, NN * 24);

  const int GG = cdiv(cdiv(NN, 16), 4);         // mgemm blocks
  const int GH96 = cdiv(NN * 6, 256);           // gather<96> half-pass blocks
  const int GH64 = cdiv(NN * 4, 256);           // gather<64> half-pass blocks

  // conv1: c1 = relu([x@W1_0 | (Ax)@W1_1 | (A^2x)@W1_2] + b1)   (bf16 activations)
  k_mgemm<96, 0><<<GG, 256, 0, stream>>>(xb, BfW1, b1, c1, nullptr, 192, 0);
  k_gatherb<96, 0><<<GH96, 256, 0, stream>>>(xb, dinv, rowptr, rec, nullptr, p1, nullptr, 0);
  k_gatherb<96, 0><<<GH96, 256, 0, stream>>>(xb, dinv, rowptr, rec, nullptr, p1, nullptr, 48);
  k_mgemm<96, 0><<<GG, 256, 0, stream>>>(p1, BfW1 + (size_t)768 * 8, b1 + 64, c1, nullptr, 192, 64);
  k_gatherb<96, 0><<<GH96, 256, 0, stream>>>(p1, dinv, rowptr, rec, nullptr, p2, nullptr, 0);
  k_gatherb<96, 0><<<GH96, 256, 0, stream>>>(p1, dinv, rowptr, rec, nullptr, p2, nullptr, 48);
  k_mgemm<96, 0><<<GG, 256, 0, stream>>>(p2, BfW1 + (size_t)2 * 768 * 8, b1 + 128, c1, nullptr, 192, 128);

  // conv2 + final linear, re-associated to 64-dim propagation:
  // out = c1@Wc0 + bc + A(z1 + A z2),  z1 = c1@Wc1, z2 = c1@Wc2
  k_mgemm<192, 2><<<GG, 256, 0, stream>>>(c1, BfWc, bc, nullptr, out, 64, 0);
  k_mgemm<192, 1><<<GG, 256, 0, stream>>>(c1, BfWc + (size_t)1536 * 8, nullptr, z1, nullptr, 64, 0);
  k_mgemm<192, 1><<<GG, 256, 0, stream>>>(c1, BfWc + (size_t)2 * 1536 * 8, nullptr, z2, nullptr, 64, 0);
  // sB = z1 + A z2
  k_gatherb<64, 1><<<GH64, 256, 0, stream>>>(z2, dinv, rowptr, rec, z1, sB, nullptr, 0);
  k_gatherb<64, 1><<<GH64, 256, 0, stream>>>(z2, dinv, rowptr, rec, z1, sB, nullptr, 32);
  // out += A sB
  k_gatherb<64, 2><<<GH64, 256, 0, stream>>>(sB, dinv, rowptr, rec, nullptr, nullptr, out, 0);
  k_gatherb<64, 2><<<GH64, 256, 0, stream>>>(sB, dinv, rowptr, rec, nullptr, nullptr, out, 32);
}

// Round 7
// 239.845 us; speedup vs baseline: 1.5316x; 1.5316x over previous
//
#include <hip/hip_runtime.h>

static constexpr int NN = 50000;
static constexpr int NE = 800000;
static constexpr int NB = (NN + 255) / 256;   // 196
static constexpr int FB = (NE + 255) / 256;   // 3125 edge blocks
static constexpr int GG = ((NN + 15) / 16 + 3) / 4;  // 782 mgemm blocks (4 waves x 16 rows)
static constexpr int GH96 = (NN * 12 + 255) / 256;   // 2344 gather<96> blocks
static constexpr int GH64 = (NN * 8 + 255) / 256;    // 1563 gather<64> blocks
static constexpr float DSCALE = 33554432.f;   // 2^25 fixed-point for degree

typedef __attribute__((ext_vector_type(8))) short bf16x8;
typedef __attribute__((ext_vector_type(4))) float f32x4;

__device__ __forceinline__ unsigned short f2bf(float f) {  // RNE
  unsigned u = __float_as_uint(f);
  u += 0x7fffu + ((u >> 16) & 1u);
  return (unsigned short)(u >> 16);
}
__device__ __forceinline__ float bf_lo(unsigned v) { return __uint_as_float(v << 16); }
__device__ __forceinline__ float bf_hi(unsigned v) { return __uint_as_float(v & 0xffff0000u); }

__device__ __forceinline__ void bf8_unpack(uint4 v, float* f) {
  f[0] = bf_lo(v.x); f[1] = bf_hi(v.x); f[2] = bf_lo(v.y); f[3] = bf_hi(v.y);
  f[4] = bf_lo(v.z); f[5] = bf_hi(v.z); f[6] = bf_lo(v.w); f[7] = bf_hi(v.w);
}
__device__ __forceinline__ uint4 bf8_pack(const float* f) {
  uint4 o;
  o.x = (unsigned)f2bf(f[0]) | ((unsigned)f2bf(f[1]) << 16);
  o.y = (unsigned)f2bf(f[2]) | ((unsigned)f2bf(f[3]) << 16);
  o.z = (unsigned)f2bf(f[4]) | ((unsigned)f2bf(f[5]) << 16);
  o.w = (unsigned)f2bf(f[6]) | ((unsigned)f2bf(f[7]) << 16);
  return o;
}

// ---- B-fragment packing (16x16x32 MFMA B layout) ----
__device__ __forceinline__ void bfrag_item(const float* __restrict__ W,
                                           unsigned short* __restrict__ Bf,
                                           int K, int idx) {
  int fragc = (K / 32) * 4 * 64;
  int mat = idx / fragc;
  int rem = idx - mat * fragc;
  int lane = rem & 63;
  int nt = (rem >> 6) & 3;
  int kt = rem >> 8;
  int lrow = lane & 15, lgrp = lane >> 4;
  const float* Wm = W + (size_t)mat * K * 64;
  float o[8];
#pragma unroll
  for (int j = 0; j < 8; ++j)
    o[j] = Wm[(size_t)(kt * 32 + lgrp * 8 + j) * 64 + nt * 16 + lrow];
  *reinterpret_cast<uint4*>(Bf + (size_t)idx * 8) = bf8_pack(o);
}

// ---- mega-init: packed init | Wc | bc | BfW1 | cast x->xb  (grid-split) ----
__global__ __launch_bounds__(256) void k_start(const float* __restrict__ x,
                                               const float* __restrict__ W1,
                                               const float* __restrict__ W2,
                                               const float* __restrict__ Wlin,
                                               const float* __restrict__ b2,
                                               const float* __restrict__ bl,
                                               unsigned long long* __restrict__ packed,
                                               float* __restrict__ Wc,
                                               float* __restrict__ bc,
                                               unsigned short* __restrict__ BfW1,
                                               unsigned short* __restrict__ xb) {
  int b = blockIdx.x, t = threadIdx.x;
  if (b < NB) {  // init packed deg/cnt (self-loop weight 1.0)
    int i = b * 256 + t;
    if (i < NN) packed[i] = ((unsigned long long)(unsigned)DSCALE) << 32;
    return;
  }
  b -= NB;
  if (b < 144) {  // Wc[p] = W2[p] @ Wl[64p:64p+64,:]
    int idx = b * 256 + t;
    int j = idx & 63;
    int k = (idx >> 6) % 192;
    int p = idx / (192 * 64);
    float s = 0.f;
    for (int m = 0; m < 64; ++m)
      s += W2[(p * 192 + k) * 64 + m] * Wlin[(p * 64 + m) * 64 + j];
    Wc[idx] = s;
    return;
  }
  b -= 144;
  if (b == 0) {  // bc
    if (t < 64) {
      float s = bl[t];
      for (int p = 0; p < 3; ++p)
        for (int m = 0; m < 64; ++m)
          s += b2[p * 64 + m] * Wlin[(p * 64 + m) * 64 + t];
      bc[t] = s;
    }
    return;
  }
  b -= 1;
  if (b < 9) {  // BfW1: 3 mats * 768 frags
    int idx = b * 256 + t;
    if (idx < 3 * 768) bfrag_item(W1, BfW1, 96, idx);
    return;
  }
  b -= 9;
  {  // cast x -> xb (float4 groups)
    int i = b * 256 + t;
    if (i < NN * 24) {
      float4 v = reinterpret_cast<const float4*>(x)[i];
      uint2 o;
      o.x = (unsigned)f2bf(v.x) | ((unsigned)f2bf(v.y) << 16);
      o.y = (unsigned)f2bf(v.z) | ((unsigned)f2bf(v.w) << 16);
      reinterpret_cast<uint2*>(xb)[i] = o;
    }
  }
}

// ---- per-edge: ONE 64-bit atomic; old value's low field = insertion position ----
__global__ void k_deg_hist(const int* __restrict__ col, const float* __restrict__ w,
                           unsigned long long* __restrict__ packed,
                           unsigned short* __restrict__ posarr) {
  int e = blockIdx.x * 256 + threadIdx.x;
  if (e < NE) {
    unsigned fx = (unsigned)(w[e] * DSCALE + 0.5f);
    unsigned long long old =
        atomicAdd(&packed[col[e]], (((unsigned long long)fx) << 32) | 1ull);
    posarr[e] = (unsigned short)(old & 0xffffull);  // in-degree < 65536 always
  }
}

// ---- scan part (block-reduce counts) + dinv, fused ----
__global__ __launch_bounds__(256) void k_scan_part(const unsigned long long* __restrict__ packed,
                                                   int* __restrict__ partial,
                                                   float* __restrict__ dinv) {
  __shared__ int s[256];
  int t = threadIdx.x;
  int i = blockIdx.x * 256 + t;
  unsigned long long pk = (i < NN) ? packed[i] : 0ull;
  if (i < NN) dinv[i] = rsqrtf((float)(pk >> 32) * (1.0f / DSCALE));
  s[t] = (i < NN) ? (int)(pk & 0xffffffffu) : 0;
  __syncthreads();
  for (int off = 128; off > 0; off >>= 1) {
    if (t < off) s[t] += s[t + off];
    __syncthreads();
  }
  if (t == 0) partial[blockIdx.x] = s[0];
}

__global__ void k_scan_base(const int* __restrict__ partial, int* __restrict__ base,
                            int* __restrict__ rowptr) {
  __shared__ int s[256];
  int t = threadIdx.x;
  s[t] = (t < NB) ? partial[t] : 0;
  __syncthreads();
  if (t == 0) {
    int run = 0;
    for (int i = 0; i < NB; ++i) { int v = s[i]; s[i] = run; run += v; }
    rowptr[NN] = run;  // == NE
  }
  __syncthreads();
  if (t < NB) base[t] = s[t];
}

__global__ __launch_bounds__(256) void k_scan_final(const unsigned long long* __restrict__ packed,
                                                    const int* __restrict__ base,
                                                    int* __restrict__ rowptr) {
  __shared__ int s[256];
  int t = threadIdx.x;
  int i = blockIdx.x * 256 + t;
  int v = (i < NN) ? (int)(packed[i] & 0xffffffffu) : 0;
  s[t] = v;
  __syncthreads();
#pragma unroll
  for (int off = 1; off < 256; off <<= 1) {
    int a = (t >= off) ? s[t - off] : 0;
    __syncthreads();
    s[t] += a;
    __syncthreads();
  }
  if (i < NN) rowptr[i] = s[t] - v + base[blockIdx.x];
}

// ---- fill CSR (NO atomics) + bfrag(Wc), grid-split ----
__global__ void k_fill(const int* __restrict__ row, const int* __restrict__ col,
                       const float* __restrict__ w, const float* __restrict__ dinv,
                       const int* __restrict__ rowptr, const unsigned short* __restrict__ posarr,
                       int2* __restrict__ rec,
                       const float* __restrict__ Wc, unsigned short* __restrict__ BfWc) {
  int b = blockIdx.x;
  if (b < FB) {
    int e = b * 256 + threadIdx.x;
    if (e < NE) {
      int r = row[e], c = col[e];
      int pos = rowptr[c] + (int)posarr[e];
      rec[pos] = make_int2(r, __float_as_int(dinv[r] * w[e] * dinv[c]));
    }
    return;
  }
  int idx = (b - FB) * 256 + threadIdx.x;
  if (idx < 3 * 1536) bfrag_item(Wc, BfWc, 192, idx);
}

// ---- propagate body (bf16 h, fp32 accum, 16B chunks, full row).
// MODE 0: outb=prop; 1: outb=add+prop; 2: outf+=prop.
template<int F, int MODE>
__device__ __forceinline__ void gather_body(int bid,
                                            const unsigned short* __restrict__ h,
                                            const float* __restrict__ dinv,
                                            const int* __restrict__ rowptr,
                                            const int2* __restrict__ rec,
                                            const unsigned short* __restrict__ add,
                                            unsigned short* __restrict__ outb,
                                            float* __restrict__ outf) {
  constexpr int CH = F / 8;
  int idx = bid * 256 + threadIdx.x;
  if (idx >= NN * CH) return;
  int node = idx / CH;
  int col = (idx - node * CH) * 8;
  const size_t base = (size_t)node * F + col;
  uint4 hv = *reinterpret_cast<const uint4*>(h + base);
  float hx[8]; bf8_unpack(hv, hx);
  float di = dinv[node];
  float d2 = di * di;
  float a[8];
#pragma unroll
  for (int j = 0; j < 8; ++j) a[j] = d2 * hx[j];
  if (MODE == 1) {
    uint4 av = *reinterpret_cast<const uint4*>(add + base);
    float ax[8]; bf8_unpack(av, ax);
#pragma unroll
    for (int j = 0; j < 8; ++j) a[j] += ax[j];
  } else if (MODE == 2) {
    float4 o0 = *reinterpret_cast<const float4*>(outf + base);
    float4 o1 = *reinterpret_cast<const float4*>(outf + base + 4);
    a[0] += o0.x; a[1] += o0.y; a[2] += o0.z; a[3] += o0.w;
    a[4] += o1.x; a[5] += o1.y; a[6] += o1.z; a[7] += o1.w;
  }
  int e0 = rowptr[node], e1 = rowptr[node + 1];
  for (int e = e0; e < e1; ++e) {
    int2 rv = rec[e];
    float nm = __int_as_float(rv.y);
    uint4 sv = *reinterpret_cast<const uint4*>(h + (size_t)rv.x * F + col);
    float sx[8]; bf8_unpack(sv, sx);
#pragma unroll
    for (int j = 0; j < 8; ++j) a[j] += nm * sx[j];
  }
  if (MODE == 2) {
    *reinterpret_cast<float4*>(outf + base) = make_float4(a[0], a[1], a[2], a[3]);
    *reinterpret_cast<float4*>(outf + base + 4) = make_float4(a[4], a[5], a[6], a[7]);
  } else {
    *reinterpret_cast<uint4*>(outb + base) = bf8_pack(a);
  }
}

// ---- MFMA GEMM body: [NN x K](bf16) @ [K x 64], 16-row tile/wave, no LDS ----
// MODE 0: bf16 out, +bias, ReLU; MODE 1: bf16 out; MODE 2: fp32 out, +bias
template<int K, int MODE>
__device__ __forceinline__ void mgemm_body(int bid,
                                           const unsigned short* __restrict__ A,
                                           const unsigned short* __restrict__ Bf,
                                           const float* __restrict__ bias,
                                           unsigned short* __restrict__ Cb,
                                           float* __restrict__ Cf,
                                           int ldc, int coff) {
  constexpr int KT = K / 32;
  int lane = threadIdx.x & 63;
  int wave = bid * 4 + (threadIdx.x >> 6);
  int r0 = wave * 16;
  if (r0 >= NN) return;
  int lrow = lane & 15, lgrp = lane >> 4;
  const unsigned short* ap = A + (size_t)(r0 + lrow) * K + lgrp * 8;
  f32x4 acc[4];
#pragma unroll
  for (int nt = 0; nt < 4; ++nt) acc[nt] = (f32x4){0.f, 0.f, 0.f, 0.f};
#pragma unroll
  for (int kt = 0; kt < KT; ++kt) {
    bf16x8 af = *reinterpret_cast<const bf16x8*>(ap + kt * 32);
#pragma unroll
    for (int nt = 0; nt < 4; ++nt) {
      bf16x8 bfr = *reinterpret_cast<const bf16x8*>(Bf + (size_t)((kt * 4 + nt) * 64 + lane) * 8);
      acc[nt] = __builtin_amdgcn_mfma_f32_16x16x32_bf16(af, bfr, acc[nt], 0, 0, 0);
    }
  }
#pragma unroll
  for (int nt = 0; nt < 4; ++nt) {
#pragma unroll
    for (int reg = 0; reg < 4; ++reg) {
      int rr = r0 + lgrp * 4 + reg;
      int cc = coff + nt * 16 + lrow;
      float v = acc[nt][reg];
      if (MODE != 1) v += bias[nt * 16 + lrow];
      if (MODE == 0) v = fmaxf(v, 0.f);
      if (MODE == 2) Cf[(size_t)rr * ldc + cc] = v;
      else           Cb[(size_t)rr * ldc + cc] = f2bf(v);
    }
  }
}

template<int K, int MODE>
__global__ __launch_bounds__(256) void k_mgemm(const unsigned short* __restrict__ A,
                                               const unsigned short* __restrict__ Bf,
                                               const float* __restrict__ bias,
                                               unsigned short* __restrict__ Cb,
                                               float* __restrict__ Cf,
                                               int ldc, int coff) {
  mgemm_body<K, MODE>(blockIdx.x, A, Bf, bias, Cb, Cf, ldc, coff);
}

// ---- fused: gather<96> (blocks [0,GH96)) + mgemm<96> (blocks [GH96, GH96+GG)) ----
__global__ __launch_bounds__(256) void k_fuse(const unsigned short* __restrict__ hsrc,
                                              const float* __restrict__ dinv,
                                              const int* __restrict__ rowptr,
                                              const int2* __restrict__ rec,
                                              unsigned short* __restrict__ pout,
                                              const unsigned short* __restrict__ Bf,
                                              const float* __restrict__ bias,
                                              unsigned short* __restrict__ c1,
                                              int coff) {
  if (blockIdx.x < GH96)
    gather_body<96, 0>(blockIdx.x, hsrc, dinv, rowptr, rec, nullptr, pout, nullptr);
  else
    mgemm_body<96, 0>(blockIdx.x - GH96, hsrc, Bf, bias, c1, nullptr, 192, coff);
}

// ---- triple K=192 GEMM sharing A=c1: out(fp32,+bc) | z1(bf16) | z2(bf16) ----
__global__ __launch_bounds__(256) void k_mgemm3(const unsigned short* __restrict__ A,
                                                const unsigned short* __restrict__ BfWc,
                                                const float* __restrict__ bc,
                                                float* __restrict__ out,
                                                unsigned short* __restrict__ z1,
                                                unsigned short* __restrict__ z2) {
  constexpr int KT = 6;
  int lane = threadIdx.x & 63;
  int wave = blockIdx.x * 4 + (threadIdx.x >> 6);
  int r0 = wave * 16;
  if (r0 >= NN) return;
  int lrow = lane & 15, lgrp = lane >> 4;
  const unsigned short* ap = A + (size_t)(r0 + lrow) * 192 + lgrp * 8;
  const unsigned short* B0 = BfWc;
  const unsigned short* B1 = BfWc + (size_t)1536 * 8;
  const unsigned short* B2 = BfWc + (size_t)2 * 1536 * 8;
  f32x4 a0[4], a1[4], a2[4];
#pragma unroll
  for (int nt = 0; nt < 4; ++nt) {
    a0[nt] = (f32x4){0.f, 0.f, 0.f, 0.f};
    a1[nt] = (f32x4){0.f, 0.f, 0.f, 0.f};
    a2[nt] = (f32x4){0.f, 0.f, 0.f, 0.f};
  }
#pragma unroll
  for (int kt = 0; kt < KT; ++kt) {
    bf16x8 af = *reinterpret_cast<const bf16x8*>(ap + kt * 32);
#pragma unroll
    for (int nt = 0; nt < 4; ++nt) {
      size_t fo = (size_t)((kt * 4 + nt) * 64 + lane) * 8;
      bf16x8 b0 = *reinterpret_cast<const bf16x8*>(B0 + fo);
      bf16x8 b1 = *reinterpret_cast<const bf16x8*>(B1 + fo);
      bf16x8 b2 = *reinterpret_cast<const bf16x8*>(B2 + fo);
      a0[nt] = __builtin_amdgcn_mfma_f32_16x16x32_bf16(af, b0, a0[nt], 0, 0, 0);
      a1[nt] = __builtin_amdgcn_mfma_f32_16x16x32_bf16(af, b1, a1[nt], 0, 0, 0);
      a2[nt] = __builtin_amdgcn_mfma_f32_16x16x32_bf16(af, b2, a2[nt], 0, 0, 0);
    }
  }
#pragma unroll
  for (int nt = 0; nt < 4; ++nt) {
#pragma unroll
    for (int reg = 0; reg < 4; ++reg) {
      int rr = r0 + lgrp * 4 + reg;
      int cc = nt * 16 + lrow;
      out[(size_t)rr * 64 + cc] = a0[nt][reg] + bc[cc];
      z1[(size_t)rr * 64 + cc] = f2bf(a1[nt][reg]);
      z2[(size_t)rr * 64 + cc] = f2bf(a2[nt][reg]);
    }
  }
}

template<int MODE>
__global__ __launch_bounds__(256) void k_gather64(const unsigned short* __restrict__ h,
                                                  const float* __restrict__ dinv,
                                                  const int* __restrict__ rowptr,
                                                  const int2* __restrict__ rec,
                                                  const unsigned short* __restrict__ add,
                                                  unsigned short* __restrict__ outb,
                                                  float* __restrict__ outf) {
  gather_body<64, MODE>(blockIdx.x, h, dinv, rowptr, rec, add, outb, outf);
}

extern "C" void kernel_launch(void* const* d_in, const int* in_sizes, int n_in,
                              void* d_out, int out_size, void* d_ws, size_t ws_size,
                              hipStream_t stream) {
  const float* x    = (const float*)d_in[0];
  const int*   ei   = (const int*)d_in[1];
  const float* ew   = (const float*)d_in[2];
  const float* W1   = (const float*)d_in[3];
  const float* b1   = (const float*)d_in[4];
  const float* W2   = (const float*)d_in[5];
  const float* b2   = (const float*)d_in[6];
  const float* Wlin = (const float*)d_in[7];
  const float* bl   = (const float*)d_in[8];
  float* out = (float*)d_out;

  const int* row = ei;
  const int* col = ei + NE;

  char* wsb = (char*)d_ws;
  unsigned long long* packed = (unsigned long long*)wsb; wsb += NN * 8;
  float* dinv    = (float*)wsb;  wsb += NN * 4;
  int*   rowptr  = (int*)wsb;    wsb += (NN + 1) * 4;
  int*   partial = (int*)wsb;    wsb += 256 * 4;
  int*   sbase   = (int*)wsb;    wsb += 256 * 4;
  unsigned short* posarr = (unsigned short*)wsb; wsb += NE * 2;
  wsb = (char*)(((size_t)wsb + 15) & ~(size_t)15);
  int2*  rec     = (int2*)wsb;   wsb += (size_t)NE * 8;
  float* Wc      = (float*)wsb;  wsb += 3 * 192 * 64 * 4;
  float* bc      = (float*)wsb;  wsb += 64 * 4;
  wsb = (char*)(((size_t)wsb + 15) & ~(size_t)15);
  unsigned short* BfW1 = (unsigned short*)wsb; wsb += (size_t)3 * 768 * 8 * 2;   // K=96 frags
  unsigned short* BfWc = (unsigned short*)wsb; wsb += (size_t)3 * 1536 * 8 * 2;  // K=192 frags
  wsb = (char*)(((size_t)wsb + 15) & ~(size_t)15);
  unsigned short* xb   = (unsigned short*)wsb; wsb += (size_t)NN * 96 * 2;
  unsigned short* c1   = (unsigned short*)wsb; wsb += (size_t)NN * 192 * 2;
  unsigned short* bufB = (unsigned short*)wsb;  // p1|p2 (2*96) then z1|z2|sB (3*64)
  unsigned short* p1 = bufB;
  unsigned short* p2 = bufB + (size_t)NN * 96;
  unsigned short* z1 = bufB;
  unsigned short* z2 = bufB + (size_t)NN * 64;
  unsigned short* sB = bufB + (size_t)NN * 128;

  // L1: init + weight prep (Wc, bc, BfW1) + cast x->xb
  const int CASTB = (NN * 24 + 255) / 256;
  k_start<<<NB + 144 + 1 + 9 + CASTB, 256, 0, stream>>>(x, W1, W2, Wlin, b2, bl,
                                                        packed, Wc, bc, BfW1, xb);
  // L2-L5: degree/count/position + dinv + rowptr
  k_deg_hist<<<FB, 256, 0, stream>>>(col, ew, packed, posarr);
  k_scan_part<<<NB, 256, 0, stream>>>(packed, partial, dinv);
  k_scan_base<<<1, 256, 0, stream>>>(partial, sbase, rowptr);
  k_scan_final<<<NB, 256, 0, stream>>>(packed, sbase, rowptr);
  // L6: atomic-free CSR fill + BfWc pack
  k_fill<<<FB + 18, 256, 0, stream>>>(row, col, ew, dinv, rowptr, posarr, rec, Wc, BfWc);

  // conv1 (fused gather+GEMM): c1 = relu([x@W1_0 | (Ax)@W1_1 | (A^2x)@W1_2] + b1)
  k_fuse<<<GH96 + GG, 256, 0, stream>>>(xb, dinv, rowptr, rec, p1, BfW1, b1, c1, 0);
  k_fuse<<<GH96 + GG, 256, 0, stream>>>(p1, dinv, rowptr, rec, p2,
                                        BfW1 + (size_t)768 * 8, b1 + 64, c1, 64);
  k_mgemm<96, 0><<<GG, 256, 0, stream>>>(p2, BfW1 + (size_t)2 * 768 * 8, b1 + 128,
                                         c1, nullptr, 192, 128);

  // conv2 + final linear (re-associated): out = c1@Wc0 + bc + A(z1 + A z2)
  k_mgemm3<<<GG, 256, 0, stream>>>(c1, BfWc, bc, out, z1, z2);
  k_gather64<1><<<GH64, 256, 0, stream>>>(z2, dinv, rowptr, rec, z1, sB, nullptr);
  k_gather64<2><<<GH64, 256, 0, stream>>>(sB, dinv, rowptr, rec, nullptr, nullptr, out);
}

// Round 8
// 214.655 us; speedup vs baseline: 1.7114x; 1.1174x over previous
//
#include <hip/hip_runtime.h>

static constexpr int NN = 50000;
static constexpr int NE = 800000;
static constexpr int NB = (NN + 255) / 256;   // 196
static constexpr int FB = (NE + 255) / 256;   // 3125 edge blocks
static constexpr int GG = ((NN + 15) / 16 + 3) / 4;  // 782 mgemm blocks (4 waves x 16 rows)
static constexpr int GH96 = (NN * 12 + 255) / 256;   // 2344 gather<96> blocks
static constexpr int GH64 = (NN * 8 + 255) / 256;    // 1563 gather<64> blocks
static constexpr float DSCALE = 33554432.f;   // 2^25 fixed-point for degree

typedef __attribute__((ext_vector_type(8))) short bf16x8;
typedef __attribute__((ext_vector_type(4))) float f32x4;

__device__ __forceinline__ unsigned short f2bf(float f) {  // RNE
  unsigned u = __float_as_uint(f);
  u += 0x7fffu + ((u >> 16) & 1u);
  return (unsigned short)(u >> 16);
}
__device__ __forceinline__ float bf_lo(unsigned v) { return __uint_as_float(v << 16); }
__device__ __forceinline__ float bf_hi(unsigned v) { return __uint_as_float(v & 0xffff0000u); }

__device__ __forceinline__ void bf8_unpack(uint4 v, float* f) {
  f[0] = bf_lo(v.x); f[1] = bf_hi(v.x); f[2] = bf_lo(v.y); f[3] = bf_hi(v.y);
  f[4] = bf_lo(v.z); f[5] = bf_hi(v.z); f[6] = bf_lo(v.w); f[7] = bf_hi(v.w);
}
__device__ __forceinline__ uint4 bf8_pack(const float* f) {
  uint4 o;
  o.x = (unsigned)f2bf(f[0]) | ((unsigned)f2bf(f[1]) << 16);
  o.y = (unsigned)f2bf(f[2]) | ((unsigned)f2bf(f[3]) << 16);
  o.z = (unsigned)f2bf(f[4]) | ((unsigned)f2bf(f[5]) << 16);
  o.w = (unsigned)f2bf(f[6]) | ((unsigned)f2bf(f[7]) << 16);
  return o;
}
__device__ __forceinline__ unsigned short f2h(float f) {
  _Float16 h = (_Float16)f;
  unsigned short u; __builtin_memcpy(&u, &h, 2);
  return u;
}
__device__ __forceinline__ float h2f(unsigned short u) {
  _Float16 h; __builtin_memcpy(&h, &u, 2);
  return (float)h;
}

// ---- B-fragment packing (16x16x32 MFMA B layout) ----
__device__ __forceinline__ void bfrag_item(const float* __restrict__ W,
                                           unsigned short* __restrict__ Bf,
                                           int K, int idx) {
  int fragc = (K / 32) * 4 * 64;
  int mat = idx / fragc;
  int rem = idx - mat * fragc;
  int lane = rem & 63;
  int nt = (rem >> 6) & 3;
  int kt = rem >> 8;
  int lrow = lane & 15, lgrp = lane >> 4;
  const float* Wm = W + (size_t)mat * K * 64;
  float o[8];
#pragma unroll
  for (int j = 0; j < 8; ++j)
    o[j] = Wm[(size_t)(kt * 32 + lgrp * 8 + j) * 64 + nt * 16 + lrow];
  *reinterpret_cast<uint4*>(Bf + (size_t)idx * 8) = bf8_pack(o);
}

// ---- weight prep: Wc | bc | BfW1 | cast x->xb  (grid-split) ----
__global__ __launch_bounds__(256) void k_start(const float* __restrict__ x,
                                               const float* __restrict__ W1,
                                               const float* __restrict__ W2,
                                               const float* __restrict__ Wlin,
                                               const float* __restrict__ b2,
                                               const float* __restrict__ bl,
                                               float* __restrict__ Wc,
                                               float* __restrict__ bc,
                                               unsigned short* __restrict__ BfW1,
                                               unsigned short* __restrict__ xb) {
  int b = blockIdx.x, t = threadIdx.x;
  if (b < 144) {  // Wc[p] = W2[p] @ Wl[64p:64p+64,:]
    int idx = b * 256 + t;
    int j = idx & 63;
    int k = (idx >> 6) % 192;
    int p = idx / (192 * 64);
    float s = 0.f;
    for (int m = 0; m < 64; ++m)
      s += W2[(p * 192 + k) * 64 + m] * Wlin[(p * 64 + m) * 64 + j];
    Wc[idx] = s;
    return;
  }
  b -= 144;
  if (b == 0) {  // bc
    if (t < 64) {
      float s = bl[t];
      for (int p = 0; p < 3; ++p)
        for (int m = 0; m < 64; ++m)
          s += b2[p * 64 + m] * Wlin[(p * 64 + m) * 64 + t];
      bc[t] = s;
    }
    return;
  }
  b -= 1;
  if (b < 9) {  // BfW1: 3 mats * 768 frags
    int idx = b * 256 + t;
    if (idx < 3 * 768) bfrag_item(W1, BfW1, 96, idx);
    return;
  }
  b -= 9;
  {  // cast x -> xb (float4 groups)
    int i = b * 256 + t;
    if (i < NN * 24) {
      float4 v = reinterpret_cast<const float4*>(x)[i];
      uint2 o;
      o.x = (unsigned)f2bf(v.x) | ((unsigned)f2bf(v.y) << 16);
      o.y = (unsigned)f2bf(v.z) | ((unsigned)f2bf(v.w) << 16);
      reinterpret_cast<uint2*>(xb)[i] = o;
    }
  }
}

// ---- per-edge: XCD-privatized 64-bit atomic (copy = blockIdx&7); old low = position ----
__global__ void k_deg_hist(const int* __restrict__ col, const float* __restrict__ w,
                           unsigned long long* __restrict__ packed8,
                           unsigned short* __restrict__ posarr) {
  int e = blockIdx.x * 256 + threadIdx.x;
  if (e < NE) {
    unsigned fx = (unsigned)(w[e] * DSCALE + 0.5f);
    int k = blockIdx.x & 7;
    unsigned long long old =
        atomicAdd(&packed8[(size_t)k * NN + col[e]], (((unsigned long long)fx) << 32) | 1ull);
    posarr[e] = (unsigned short)(old & 0xffffull);  // per-copy in-degree < 65536
  }
}

// ---- scan part: sum 8 copies -> cnttot, dinv, per-copy offsets; block partial ----
__global__ __launch_bounds__(256) void k_scan_part(const unsigned long long* __restrict__ packed8,
                                                   int* __restrict__ partial,
                                                   float* __restrict__ dinv,
                                                   int* __restrict__ cnttot,
                                                   unsigned short* __restrict__ cumoff) {
  __shared__ int s[256];
  int t = threadIdx.x;
  int i = blockIdx.x * 256 + t;
  int total = 0;
  if (i < NN) {
    unsigned long long wsum = 0;
    int run = 0;
    unsigned short co[8];
#pragma unroll
    for (int k = 0; k < 8; ++k) {
      unsigned long long pk = packed8[(size_t)k * NN + i];
      co[k] = (unsigned short)run;
      run += (int)(pk & 0xffffffffu);
      wsum += (pk >> 32);
    }
    total = run;
    dinv[i] = rsqrtf(1.0f + (float)wsum * (1.0f / DSCALE));  // +1 self-loop
    cnttot[i] = total;
    uint4 pk4;
    pk4.x = (unsigned)co[0] | ((unsigned)co[1] << 16);
    pk4.y = (unsigned)co[2] | ((unsigned)co[3] << 16);
    pk4.z = (unsigned)co[4] | ((unsigned)co[5] << 16);
    pk4.w = (unsigned)co[6] | ((unsigned)co[7] << 16);
    reinterpret_cast<uint4*>(cumoff)[i] = pk4;
  }
  s[t] = total;
  __syncthreads();
  for (int off = 128; off > 0; off >>= 1) {
    if (t < off) s[t] += s[t + off];
    __syncthreads();
  }
  if (t == 0) partial[blockIdx.x] = s[0];
}

// ---- scan final: in-block base over partials + local scan -> rowptr ----
__global__ __launch_bounds__(256) void k_scan_final(const int* __restrict__ cnttot,
                                                    const int* __restrict__ partial,
                                                    int* __restrict__ rowptr) {
  __shared__ int s[256], p[256];
  int t = threadIdx.x;
  p[t] = (t < NB) ? partial[t] : 0;
  __syncthreads();
#pragma unroll
  for (int off = 1; off < 256; off <<= 1) {
    int a = (t >= off) ? p[t - off] : 0;
    __syncthreads();
    p[t] += a;
    __syncthreads();
  }
  int base = (blockIdx.x > 0) ? p[blockIdx.x - 1] : 0;
  int i = blockIdx.x * 256 + t;
  int v = (i < NN) ? cnttot[i] : 0;
  s[t] = v;
  __syncthreads();
#pragma unroll
  for (int off = 1; off < 256; off <<= 1) {
    int a = (t >= off) ? s[t - off] : 0;
    __syncthreads();
    s[t] += a;
    __syncthreads();
  }
  if (i < NN) rowptr[i] = s[t] - v + base;
  if (blockIdx.x == 0 && t == 0) rowptr[NN] = NE;
}

// ---- fill CSR (no atomics, 4B packed records) + bfrag(Wc), grid-split ----
__global__ void k_fill(const int* __restrict__ row, const int* __restrict__ col,
                       const float* __restrict__ w, const float* __restrict__ dinv,
                       const int* __restrict__ rowptr,
                       const unsigned short* __restrict__ posarr,
                       const unsigned short* __restrict__ cumoff,
                       unsigned* __restrict__ rec,
                       const float* __restrict__ Wc, unsigned short* __restrict__ BfWc) {
  int b = blockIdx.x;
  if (b < FB) {
    int e = b * 256 + threadIdx.x;
    if (e < NE) {
      int r = row[e], c = col[e];
      int k = (e >> 8) & 7;
      int pos = rowptr[c] + (int)cumoff[c * 8 + k] + (int)posarr[e];
      float nrm = dinv[r] * w[e] * dinv[c];
      rec[pos] = (unsigned)r | ((unsigned)f2h(nrm) << 16);
    }
    return;
  }
  int idx = (b - FB) * 256 + threadIdx.x;
  if (idx < 3 * 1536) bfrag_item(Wc, BfWc, 192, idx);
}

// ---- propagate body (bf16 h, fp32 accum, fp16 nrm, unroll-4 MLP).
// MODE 0: outb=prop; 1: outb=add+prop; 2: outf+=prop.
template<int F, int MODE>
__device__ __forceinline__ void gather_body(int bid,
                                            const unsigned short* __restrict__ h,
                                            const float* __restrict__ dinv,
                                            const int* __restrict__ rowptr,
                                            const unsigned* __restrict__ rec,
                                            const unsigned short* __restrict__ add,
                                            unsigned short* __restrict__ outb,
                                            float* __restrict__ outf) {
  constexpr int CH = F / 8;
  int idx = bid * 256 + threadIdx.x;
  if (idx >= NN * CH) return;
  int node = idx / CH;
  int col = (idx - node * CH) * 8;
  const size_t base = (size_t)node * F + col;
  uint4 hv = *reinterpret_cast<const uint4*>(h + base);
  float hx[8]; bf8_unpack(hv, hx);
  float d2 = dinv[node]; d2 *= d2;
  float a[8];
#pragma unroll
  for (int j = 0; j < 8; ++j) a[j] = d2 * hx[j];
  if (MODE == 1) {
    uint4 av = *reinterpret_cast<const uint4*>(add + base);
    float ax[8]; bf8_unpack(av, ax);
#pragma unroll
    for (int j = 0; j < 8; ++j) a[j] += ax[j];
  } else if (MODE == 2) {
    float4 o0 = *reinterpret_cast<const float4*>(outf + base);
    float4 o1 = *reinterpret_cast<const float4*>(outf + base + 4);
    a[0] += o0.x; a[1] += o0.y; a[2] += o0.z; a[3] += o0.w;
    a[4] += o1.x; a[5] += o1.y; a[6] += o1.z; a[7] += o1.w;
  }
  int e = rowptr[node], e1 = rowptr[node + 1];
  for (; e + 4 <= e1; e += 4) {
    unsigned rv0 = rec[e], rv1 = rec[e + 1], rv2 = rec[e + 2], rv3 = rec[e + 3];
    uint4 s0 = *reinterpret_cast<const uint4*>(h + (size_t)(rv0 & 0xffffu) * F + col);
    uint4 s1 = *reinterpret_cast<const uint4*>(h + (size_t)(rv1 & 0xffffu) * F + col);
    uint4 s2 = *reinterpret_cast<const uint4*>(h + (size_t)(rv2 & 0xffffu) * F + col);
    uint4 s3 = *reinterpret_cast<const uint4*>(h + (size_t)(rv3 & 0xffffu) * F + col);
    float nm0 = h2f((unsigned short)(rv0 >> 16));
    float nm1 = h2f((unsigned short)(rv1 >> 16));
    float nm2 = h2f((unsigned short)(rv2 >> 16));
    float nm3 = h2f((unsigned short)(rv3 >> 16));
    float sx[8];
    bf8_unpack(s0, sx);
#pragma unroll
    for (int j = 0; j < 8; ++j) a[j] += nm0 * sx[j];
    bf8_unpack(s1, sx);
#pragma unroll
    for (int j = 0; j < 8; ++j) a[j] += nm1 * sx[j];
    bf8_unpack(s2, sx);
#pragma unroll
    for (int j = 0; j < 8; ++j) a[j] += nm2 * sx[j];
    bf8_unpack(s3, sx);
#pragma unroll
    for (int j = 0; j < 8; ++j) a[j] += nm3 * sx[j];
  }
  for (; e < e1; ++e) {
    unsigned rv = rec[e];
    uint4 sv = *reinterpret_cast<const uint4*>(h + (size_t)(rv & 0xffffu) * F + col);
    float nm = h2f((unsigned short)(rv >> 16));
    float sx[8]; bf8_unpack(sv, sx);
#pragma unroll
    for (int j = 0; j < 8; ++j) a[j] += nm * sx[j];
  }
  if (MODE == 2) {
    *reinterpret_cast<float4*>(outf + base) = make_float4(a[0], a[1], a[2], a[3]);
    *reinterpret_cast<float4*>(outf + base + 4) = make_float4(a[4], a[5], a[6], a[7]);
  } else {
    *reinterpret_cast<uint4*>(outb + base) = bf8_pack(a);
  }
}

// ---- MFMA GEMM body: [NN x K](bf16) @ [K x 64], 16-row tile/wave, no LDS ----
// MODE 0: bf16 out, +bias, ReLU; MODE 1: bf16 out; MODE 2: fp32 out, +bias
template<int K, int MODE>
__device__ __forceinline__ void mgemm_body(int bid,
                                           const unsigned short* __restrict__ A,
                                           const unsigned short* __restrict__ Bf,
                                           const float* __restrict__ bias,
                                           unsigned short* __restrict__ Cb,
                                           float* __restrict__ Cf,
                                           int ldc, int coff) {
  constexpr int KT = K / 32;
  int lane = threadIdx.x & 63;
  int wave = bid * 4 + (threadIdx.x >> 6);
  int r0 = wave * 16;
  if (r0 >= NN) return;
  int lrow = lane & 15, lgrp = lane >> 4;
  const unsigned short* ap = A + (size_t)(r0 + lrow) * K + lgrp * 8;
  f32x4 acc[4];
#pragma unroll
  for (int nt = 0; nt < 4; ++nt) acc[nt] = (f32x4){0.f, 0.f, 0.f, 0.f};
#pragma unroll
  for (int kt = 0; kt < KT; ++kt) {
    bf16x8 af = *reinterpret_cast<const bf16x8*>(ap + kt * 32);
#pragma unroll
    for (int nt = 0; nt < 4; ++nt) {
      bf16x8 bfr = *reinterpret_cast<const bf16x8*>(Bf + (size_t)((kt * 4 + nt) * 64 + lane) * 8);
      acc[nt] = __builtin_amdgcn_mfma_f32_16x16x32_bf16(af, bfr, acc[nt], 0, 0, 0);
    }
  }
#pragma unroll
  for (int nt = 0; nt < 4; ++nt) {
#pragma unroll
    for (int reg = 0; reg < 4; ++reg) {
      int rr = r0 + lgrp * 4 + reg;
      int cc = coff + nt * 16 + lrow;
      float v = acc[nt][reg];
      if (MODE != 1) v += bias[nt * 16 + lrow];
      if (MODE == 0) v = fmaxf(v, 0.f);
      if (MODE == 2) Cf[(size_t)rr * ldc + cc] = v;
      else           Cb[(size_t)rr * ldc + cc] = f2bf(v);
    }
  }
}

template<int K, int MODE>
__global__ __launch_bounds__(256) void k_mgemm(const unsigned short* __restrict__ A,
                                               const unsigned short* __restrict__ Bf,
                                               const float* __restrict__ bias,
                                               unsigned short* __restrict__ Cb,
                                               float* __restrict__ Cf,
                                               int ldc, int coff) {
  mgemm_body<K, MODE>(blockIdx.x, A, Bf, bias, Cb, Cf, ldc, coff);
}

// ---- fused: gather<96> + mgemm<96> ----
__global__ __launch_bounds__(256) void k_fuse(const unsigned short* __restrict__ hsrc,
                                              const float* __restrict__ dinv,
                                              const int* __restrict__ rowptr,
                                              const unsigned* __restrict__ rec,
                                              unsigned short* __restrict__ pout,
                                              const unsigned short* __restrict__ Bf,
                                              const float* __restrict__ bias,
                                              unsigned short* __restrict__ c1,
                                              int coff) {
  if (blockIdx.x < GH96)
    gather_body<96, 0>(blockIdx.x, hsrc, dinv, rowptr, rec, nullptr, pout, nullptr);
  else
    mgemm_body<96, 0>(blockIdx.x - GH96, hsrc, Bf, bias, c1, nullptr, 192, coff);
}

// ---- triple K=192 GEMM sharing A=c1: out(fp32,+bc) | z1(bf16) | z2(bf16) ----
__global__ __launch_bounds__(256) void k_mgemm3(const unsigned short* __restrict__ A,
                                                const unsigned short* __restrict__ BfWc,
                                                const float* __restrict__ bc,
                                                float* __restrict__ out,
                                                unsigned short* __restrict__ z1,
                                                unsigned short* __restrict__ z2) {
  constexpr int KT = 6;
  int lane = threadIdx.x & 63;
  int wave = blockIdx.x * 4 + (threadIdx.x >> 6);
  int r0 = wave * 16;
  if (r0 >= NN) return;
  int lrow = lane & 15, lgrp = lane >> 4;
  const unsigned short* ap = A + (size_t)(r0 + lrow) * 192 + lgrp * 8;
  const unsigned short* B0 = BfWc;
  const unsigned short* B1 = BfWc + (size_t)1536 * 8;
  const unsigned short* B2 = BfWc + (size_t)2 * 1536 * 8;
  f32x4 a0[4], a1[4], a2[4];
#pragma unroll
  for (int nt = 0; nt < 4; ++nt) {
    a0[nt] = (f32x4){0.f, 0.f, 0.f, 0.f};
    a1[nt] = (f32x4){0.f, 0.f, 0.f, 0.f};
    a2[nt] = (f32x4){0.f, 0.f, 0.f, 0.f};
  }
#pragma unroll
  for (int kt = 0; kt < KT; ++kt) {
    bf16x8 af = *reinterpret_cast<const bf16x8*>(ap + kt * 32);
#pragma unroll
    for (int nt = 0; nt < 4; ++nt) {
      size_t fo = (size_t)((kt * 4 + nt) * 64 + lane) * 8;
      bf16x8 b0 = *reinterpret_cast<const bf16x8*>(B0 + fo);
      bf16x8 b1 = *reinterpret_cast<const bf16x8*>(B1 + fo);
      bf16x8 b2 = *reinterpret_cast<const bf16x8*>(B2 + fo);
      a0[nt] = __builtin_amdgcn_mfma_f32_16x16x32_bf16(af, b0, a0[nt], 0, 0, 0);
      a1[nt] = __builtin_amdgcn_mfma_f32_16x16x32_bf16(af, b1, a1[nt], 0, 0, 0);
      a2[nt] = __builtin_amdgcn_mfma_f32_16x16x32_bf16(af, b2, a2[nt], 0, 0, 0);
    }
  }
#pragma unroll
  for (int nt = 0; nt < 4; ++nt) {
#pragma unroll
    for (int reg = 0; reg < 4; ++reg) {
      int rr = r0 + lgrp * 4 + reg;
      int cc = nt * 16 + lrow;
      out[(size_t)rr * 64 + cc] = a0[nt][reg] + bc[cc];
      z1[(size_t)rr * 64 + cc] = f2bf(a1[nt][reg]);
      z2[(size_t)rr * 64 + cc] = f2bf(a2[nt][reg]);
    }
  }
}

template<int MODE>
__global__ __launch_bounds__(256) void k_gather64(const unsigned short* __restrict__ h,
                                                  const float* __restrict__ dinv,
                                                  const int* __restrict__ rowptr,
                                                  const unsigned* __restrict__ rec,
                                                  const unsigned short* __restrict__ add,
                                                  unsigned short* __restrict__ outb,
                                                  float* __restrict__ outf) {
  gather_body<64, MODE>(blockIdx.x, h, dinv, rowptr, rec, add, outb, outf);
}

extern "C" void kernel_launch(void* const* d_in, const int* in_sizes, int n_in,
                              void* d_out, int out_size, void* d_ws, size_t ws_size,
                              hipStream_t stream) {
  const float* x    = (const float*)d_in[0];
  const int*   ei   = (const int*)d_in[1];
  const float* ew   = (const float*)d_in[2];
  const float* W1   = (const float*)d_in[3];
  const float* b1   = (const float*)d_in[4];
  const float* W2   = (const float*)d_in[5];
  const float* b2   = (const float*)d_in[6];
  const float* Wlin = (const float*)d_in[7];
  const float* bl   = (const float*)d_in[8];
  float* out = (float*)d_out;

  const int* row = ei;
  const int* col = ei + NE;

  char* wsb = (char*)d_ws;
  unsigned long long* packed8 = (unsigned long long*)wsb; wsb += (size_t)8 * NN * 8;
  float* dinv    = (float*)wsb;  wsb += NN * 4;
  int*   cnttot  = (int*)wsb;    wsb += NN * 4;
  int*   rowptr  = (int*)wsb;    wsb += (NN + 1) * 4;
  int*   partial = (int*)wsb;    wsb += 256 * 4;
  wsb = (char*)(((size_t)wsb + 15) & ~(size_t)15);
  unsigned short* cumoff = (unsigned short*)wsb; wsb += (size_t)NN * 8 * 2;
  unsigned short* posarr = (unsigned short*)wsb; wsb += NE * 2;
  wsb = (char*)(((size_t)wsb + 15) & ~(size_t)15);
  unsigned* rec  = (unsigned*)wsb; wsb += (size_t)NE * 4;
  float* Wc      = (float*)wsb;  wsb += 3 * 192 * 64 * 4;
  float* bc      = (float*)wsb;  wsb += 64 * 4;
  wsb = (char*)(((size_t)wsb + 15) & ~(size_t)15);
  unsigned short* BfW1 = (unsigned short*)wsb; wsb += (size_t)3 * 768 * 8 * 2;   // K=96 frags
  unsigned short* BfWc = (unsigned short*)wsb; wsb += (size_t)3 * 1536 * 8 * 2;  // K=192 frags
  wsb = (char*)(((size_t)wsb + 15) & ~(size_t)15);
  unsigned short* xb   = (unsigned short*)wsb; wsb += (size_t)NN * 96 * 2;
  unsigned short* c1   = (unsigned short*)wsb; wsb += (size_t)NN * 192 * 2;
  unsigned short* bufB = (unsigned short*)wsb;  // p1|p2 (2*96) then z1|z2|sB (3*64)
  unsigned short* p1 = bufB;
  unsigned short* p2 = bufB + (size_t)NN * 96;
  unsigned short* z1 = bufB;
  unsigned short* z2 = bufB + (size_t)NN * 64;
  unsigned short* sB = bufB + (size_t)NN * 128;

  // zero privatized histograms (self-loop folded into scan)
  hipMemsetAsync(packed8, 0, (size_t)8 * NN * 8, stream);
  // weight prep + cast
  const int CASTB = (NN * 24 + 255) / 256;
  k_start<<<144 + 1 + 9 + CASTB, 256, 0, stream>>>(x, W1, W2, Wlin, b2, bl, Wc, bc, BfW1, xb);
  // degree/count/position (XCD-privatized) + dinv + rowptr
  k_deg_hist<<<FB, 256, 0, stream>>>(col, ew, packed8, posarr);
  k_scan_part<<<NB, 256, 0, stream>>>(packed8, partial, dinv, cnttot, cumoff);
  k_scan_final<<<NB, 256, 0, stream>>>(cnttot, partial, rowptr);
  // atomic-free CSR fill (4B records) + BfWc pack
  k_fill<<<FB + 18, 256, 0, stream>>>(row, col, ew, dinv, rowptr, posarr, cumoff, rec, Wc, BfWc);

  // conv1 (fused gather+GEMM): c1 = relu([x@W1_0 | (Ax)@W1_1 | (A^2x)@W1_2] + b1)
  k_fuse<<<GH96 + GG, 256, 0, stream>>>(xb, dinv, rowptr, rec, p1, BfW1, b1, c1, 0);
  k_fuse<<<GH96 + GG, 256, 0, stream>>>(p1, dinv, rowptr, rec, p2,
                                        BfW1 + (size_t)768 * 8, b1 + 64, c1, 64);
  k_mgemm<96, 0><<<GG, 256, 0, stream>>>(p2, BfW1 + (size_t)2 * 768 * 8, b1 + 128,
                                         c1, nullptr, 192, 128);

  // conv2 + final linear (re-associated): out = c1@Wc0 + bc + A(z1 + A z2)
  k_mgemm3<<<GG, 256, 0, stream>>>(c1, BfWc, bc, out, z1, z2);
  k_gather64<1><<<GH64, 256, 0, stream>>>(z2, dinv, rowptr, rec, z1, sB, nullptr);
  k_gather64<2><<<GH64, 256, 0, stream>>>(sB, dinv, rowptr, rec, nullptr, nullptr, out);
}

// Round 9
// 210.894 us; speedup vs baseline: 1.7419x; 1.0178x over previous
//
#include <hip/hip_runtime.h>

static constexpr int NN = 50000;
static constexpr int NE = 800000;
static constexpr int NB = (NN + 255) / 256;   // 196
static constexpr int FB = (NE + 255) / 256;   // 3125 edge blocks
static constexpr int GG = ((NN + 15) / 16 + 3) / 4;  // 782 mgemm blocks (4 waves x 16 rows)
static constexpr int GH96 = (NN * 12 + 255) / 256;   // 2344 gather<96> blocks
static constexpr int GH64 = (NN * 8 + 255) / 256;    // 1563 gather<64> blocks
static constexpr int ZB = (NN * 8 * 8 / 16 + 255) / 256;  // 782 zero blocks (uint4)
static constexpr float DSCALE = 33554432.f;   // 2^25 fixed-point for degree

typedef __attribute__((ext_vector_type(8))) short bf16x8;
typedef __attribute__((ext_vector_type(4))) float f32x4;

__device__ __forceinline__ unsigned short f2bf(float f) {  // RNE
  unsigned u = __float_as_uint(f);
  u += 0x7fffu + ((u >> 16) & 1u);
  return (unsigned short)(u >> 16);
}
__device__ __forceinline__ float bf_lo(unsigned v) { return __uint_as_float(v << 16); }
__device__ __forceinline__ float bf_hi(unsigned v) { return __uint_as_float(v & 0xffff0000u); }

__device__ __forceinline__ void bf8_unpack(uint4 v, float* f) {
  f[0] = bf_lo(v.x); f[1] = bf_hi(v.x); f[2] = bf_lo(v.y); f[3] = bf_hi(v.y);
  f[4] = bf_lo(v.z); f[5] = bf_hi(v.z); f[6] = bf_lo(v.w); f[7] = bf_hi(v.w);
}
__device__ __forceinline__ uint4 bf8_pack(const float* f) {
  uint4 o;
  o.x = (unsigned)f2bf(f[0]) | ((unsigned)f2bf(f[1]) << 16);
  o.y = (unsigned)f2bf(f[2]) | ((unsigned)f2bf(f[3]) << 16);
  o.z = (unsigned)f2bf(f[4]) | ((unsigned)f2bf(f[5]) << 16);
  o.w = (unsigned)f2bf(f[6]) | ((unsigned)f2bf(f[7]) << 16);
  return o;
}
__device__ __forceinline__ unsigned short f2h(float f) {
  _Float16 h = (_Float16)f;
  unsigned short u; __builtin_memcpy(&u, &h, 2);
  return u;
}
__device__ __forceinline__ float h2f(unsigned short u) {
  _Float16 h; __builtin_memcpy(&h, &u, 2);
  return (float)h;
}

// ---- zero the privatized histograms (fast replacement for hipMemsetAsync) ----
__global__ __launch_bounds__(256) void k_zero(uint4* __restrict__ p) {
  int i = blockIdx.x * 256 + threadIdx.x;
  if (i < NN * 8 * 8 / 16) p[i] = make_uint4(0u, 0u, 0u, 0u);
}

// ---- B-fragment packing (16x16x32 MFMA B layout) ----
__device__ __forceinline__ void bfrag_item(const float* __restrict__ W,
                                           unsigned short* __restrict__ Bf,
                                           int K, int idx) {
  int fragc = (K / 32) * 4 * 64;
  int mat = idx / fragc;
  int rem = idx - mat * fragc;
  int lane = rem & 63;
  int nt = (rem >> 6) & 3;
  int kt = rem >> 8;
  int lrow = lane & 15, lgrp = lane >> 4;
  const float* Wm = W + (size_t)mat * K * 64;
  float o[8];
#pragma unroll
  for (int j = 0; j < 8; ++j)
    o[j] = Wm[(size_t)(kt * 32 + lgrp * 8 + j) * 64 + nt * 16 + lrow];
  *reinterpret_cast<uint4*>(Bf + (size_t)idx * 8) = bf8_pack(o);
}

// ---- mega-start: deg_hist | Wc | bc | BfW1 | cast x->xb  (grid-split) ----
__global__ __launch_bounds__(256) void k_start(const float* __restrict__ x,
                                               const float* __restrict__ W1,
                                               const float* __restrict__ W2,
                                               const float* __restrict__ Wlin,
                                               const float* __restrict__ b2,
                                               const float* __restrict__ bl,
                                               const int* __restrict__ col,
                                               const float* __restrict__ ew,
                                               unsigned long long* __restrict__ packed8,
                                               unsigned short* __restrict__ posarr,
                                               float* __restrict__ Wc,
                                               float* __restrict__ bc,
                                               unsigned short* __restrict__ BfW1,
                                               unsigned short* __restrict__ xb) {
  int b = blockIdx.x, t = threadIdx.x;
  if (b < FB) {  // per-edge histogram: XCD-privatized 64-bit atomic; old low = position
    int e = b * 256 + t;
    if (e < NE) {
      unsigned fx = (unsigned)(ew[e] * DSCALE + 0.5f);
      int k = b & 7;
      unsigned long long old =
          atomicAdd(&packed8[(size_t)k * NN + col[e]], (((unsigned long long)fx) << 32) | 1ull);
      posarr[e] = (unsigned short)(old & 0xffffull);
    }
    return;
  }
  b -= FB;
  if (b < 144) {  // Wc[p] = W2[p] @ Wl[64p:64p+64,:]
    int idx = b * 256 + t;
    int j = idx & 63;
    int k = (idx >> 6) % 192;
    int p = idx / (192 * 64);
    float s = 0.f;
    for (int m = 0; m < 64; ++m)
      s += W2[(p * 192 + k) * 64 + m] * Wlin[(p * 64 + m) * 64 + j];
    Wc[idx] = s;
    return;
  }
  b -= 144;
  if (b == 0) {  // bc
    if (t < 64) {
      float s = bl[t];
      for (int p = 0; p < 3; ++p)
        for (int m = 0; m < 64; ++m)
          s += b2[p * 64 + m] * Wlin[(p * 64 + m) * 64 + t];
      bc[t] = s;
    }
    return;
  }
  b -= 1;
  if (b < 9) {  // BfW1: 3 mats * 768 frags
    int idx = b * 256 + t;
    if (idx < 3 * 768) bfrag_item(W1, BfW1, 96, idx);
    return;
  }
  b -= 9;
  {  // cast x -> xb (float4 groups)
    int i = b * 256 + t;
    if (i < NN * 24) {
      float4 v = reinterpret_cast<const float4*>(x)[i];
      uint2 o;
      o.x = (unsigned)f2bf(v.x) | ((unsigned)f2bf(v.y) << 16);
      o.y = (unsigned)f2bf(v.z) | ((unsigned)f2bf(v.w) << 16);
      reinterpret_cast<uint2*>(xb)[i] = o;
    }
  }
}

// ---- scan part: sum 8 copies -> cnttot, dinv, per-copy offsets; block partial ----
__global__ __launch_bounds__(256) void k_scan_part(const unsigned long long* __restrict__ packed8,
                                                   int* __restrict__ partial,
                                                   float* __restrict__ dinv,
                                                   int* __restrict__ cnttot,
                                                   unsigned short* __restrict__ cumoff) {
  __shared__ int s[256];
  int t = threadIdx.x;
  int i = blockIdx.x * 256 + t;
  int total = 0;
  if (i < NN) {
    unsigned long long wsum = 0;
    int run = 0;
    unsigned short co[8];
#pragma unroll
    for (int k = 0; k < 8; ++k) {
      unsigned long long pk = packed8[(size_t)k * NN + i];
      co[k] = (unsigned short)run;
      run += (int)(pk & 0xffffffffu);
      wsum += (pk >> 32);
    }
    total = run;
    dinv[i] = rsqrtf(1.0f + (float)wsum * (1.0f / DSCALE));  // +1 self-loop
    cnttot[i] = total;
    uint4 pk4;
    pk4.x = (unsigned)co[0] | ((unsigned)co[1] << 16);
    pk4.y = (unsigned)co[2] | ((unsigned)co[3] << 16);
    pk4.z = (unsigned)co[4] | ((unsigned)co[5] << 16);
    pk4.w = (unsigned)co[6] | ((unsigned)co[7] << 16);
    reinterpret_cast<uint4*>(cumoff)[i] = pk4;
  }
  s[t] = total;
  __syncthreads();
  for (int off = 128; off > 0; off >>= 1) {
    if (t < off) s[t] += s[t + off];
    __syncthreads();
  }
  if (t == 0) partial[blockIdx.x] = s[0];
}

// ---- scan final: in-block base over partials + local scan -> rowptr ----
__global__ __launch_bounds__(256) void k_scan_final(const int* __restrict__ cnttot,
                                                    const int* __restrict__ partial,
                                                    int* __restrict__ rowptr) {
  __shared__ int s[256], p[256];
  int t = threadIdx.x;
  p[t] = (t < NB) ? partial[t] : 0;
  __syncthreads();
#pragma unroll
  for (int off = 1; off < 256; off <<= 1) {
    int a = (t >= off) ? p[t - off] : 0;
    __syncthreads();
    p[t] += a;
    __syncthreads();
  }
  int base = (blockIdx.x > 0) ? p[blockIdx.x - 1] : 0;
  int i = blockIdx.x * 256 + t;
  int v = (i < NN) ? cnttot[i] : 0;
  s[t] = v;
  __syncthreads();
#pragma unroll
  for (int off = 1; off < 256; off <<= 1) {
    int a = (t >= off) ? s[t - off] : 0;
    __syncthreads();
    s[t] += a;
    __syncthreads();
  }
  if (i < NN) rowptr[i] = s[t] - v + base;
  if (blockIdx.x == 0 && t == 0) rowptr[NN] = NE;
}

// ---- fill CSR (no atomics, 4B packed records) + bfrag(Wc), grid-split ----
__global__ void k_fill(const int* __restrict__ row, const int* __restrict__ col,
                       const float* __restrict__ w, const float* __restrict__ dinv,
                       const int* __restrict__ rowptr,
                       const unsigned short* __restrict__ posarr,
                       const unsigned short* __restrict__ cumoff,
                       unsigned* __restrict__ rec,
                       const float* __restrict__ Wc, unsigned short* __restrict__ BfWc) {
  int b = blockIdx.x;
  if (b < FB) {
    int e = b * 256 + threadIdx.x;
    if (e < NE) {
      int r = row[e], c = col[e];
      int k = b & 7;
      int pos = rowptr[c] + (int)cumoff[c * 8 + k] + (int)posarr[e];
      float nrm = dinv[r] * w[e] * dinv[c];
      rec[pos] = (unsigned)r | ((unsigned)f2h(nrm) << 16);
    }
    return;
  }
  int idx = (b - FB) * 256 + threadIdx.x;
  if (idx < 3 * 1536) bfrag_item(Wc, BfWc, 192, idx);
}

// ---- propagate body (bf16 h, fp32 accum, fp16 nrm, unroll-4 MLP).
// MODE 0: outb=prop; 1: outb=add+prop; 2: outf+=prop.
template<int F, int MODE>
__device__ __forceinline__ void gather_body(int bid,
                                            const unsigned short* __restrict__ h,
                                            const float* __restrict__ dinv,
                                            const int* __restrict__ rowptr,
                                            const unsigned* __restrict__ rec,
                                            const unsigned short* __restrict__ add,
                                            unsigned short* __restrict__ outb,
                                            float* __restrict__ outf) {
  constexpr int CH = F / 8;
  int idx = bid * 256 + threadIdx.x;
  if (idx >= NN * CH) return;
  int node = idx / CH;
  int col = (idx - node * CH) * 8;
  const size_t base = (size_t)node * F + col;
  uint4 hv = *reinterpret_cast<const uint4*>(h + base);
  float hx[8]; bf8_unpack(hv, hx);
  float d2 = dinv[node]; d2 *= d2;
  float a[8];
#pragma unroll
  for (int j = 0; j < 8; ++j) a[j] = d2 * hx[j];
  if (MODE == 1) {
    uint4 av = *reinterpret_cast<const uint4*>(add + base);
    float ax[8]; bf8_unpack(av, ax);
#pragma unroll
    for (int j = 0; j < 8; ++j) a[j] += ax[j];
  } else if (MODE == 2) {
    float4 o0 = *reinterpret_cast<const float4*>(outf + base);
    float4 o1 = *reinterpret_cast<const float4*>(outf + base + 4);
    a[0] += o0.x; a[1] += o0.y; a[2] += o0.z; a[3] += o0.w;
    a[4] += o1.x; a[5] += o1.y; a[6] += o1.z; a[7] += o1.w;
  }
  int e = rowptr[node], e1 = rowptr[node + 1];
  for (; e + 4 <= e1; e += 4) {
    unsigned rv0 = rec[e], rv1 = rec[e + 1], rv2 = rec[e + 2], rv3 = rec[e + 3];
    uint4 s0 = *reinterpret_cast<const uint4*>(h + (size_t)(rv0 & 0xffffu) * F + col);
    uint4 s1 = *reinterpret_cast<const uint4*>(h + (size_t)(rv1 & 0xffffu) * F + col);
    uint4 s2 = *reinterpret_cast<const uint4*>(h + (size_t)(rv2 & 0xffffu) * F + col);
    uint4 s3 = *reinterpret_cast<const uint4*>(h + (size_t)(rv3 & 0xffffu) * F + col);
    float nm0 = h2f((unsigned short)(rv0 >> 16));
    float nm1 = h2f((unsigned short)(rv1 >> 16));
    float nm2 = h2f((unsigned short)(rv2 >> 16));
    float nm3 = h2f((unsigned short)(rv3 >> 16));
    float sx[8];
    bf8_unpack(s0, sx);
#pragma unroll
    for (int j = 0; j < 8; ++j) a[j] += nm0 * sx[j];
    bf8_unpack(s1, sx);
#pragma unroll
    for (int j = 0; j < 8; ++j) a[j] += nm1 * sx[j];
    bf8_unpack(s2, sx);
#pragma unroll
    for (int j = 0; j < 8; ++j) a[j] += nm2 * sx[j];
    bf8_unpack(s3, sx);
#pragma unroll
    for (int j = 0; j < 8; ++j) a[j] += nm3 * sx[j];
  }
  for (; e < e1; ++e) {
    unsigned rv = rec[e];
    uint4 sv = *reinterpret_cast<const uint4*>(h + (size_t)(rv & 0xffffu) * F + col);
    float nm = h2f((unsigned short)(rv >> 16));
    float sx[8]; bf8_unpack(sv, sx);
#pragma unroll
    for (int j = 0; j < 8; ++j) a[j] += nm * sx[j];
  }
  if (MODE == 2) {
    *reinterpret_cast<float4*>(outf + base) = make_float4(a[0], a[1], a[2], a[3]);
    *reinterpret_cast<float4*>(outf + base + 4) = make_float4(a[4], a[5], a[6], a[7]);
  } else {
    *reinterpret_cast<uint4*>(outb + base) = bf8_pack(a);
  }
}

// ---- MFMA GEMM body: [NN x K](bf16) @ [K x 64], 16-row tile/wave, no LDS ----
// MODE 0: bf16 out, +bias, ReLU; MODE 1: bf16 out; MODE 2: fp32 out, +bias
template<int K, int MODE>
__device__ __forceinline__ void mgemm_body(int bid,
                                           const unsigned short* __restrict__ A,
                                           const unsigned short* __restrict__ Bf,
                                           const float* __restrict__ bias,
                                           unsigned short* __restrict__ Cb,
                                           float* __restrict__ Cf,
                                           int ldc, int coff) {
  constexpr int KT = K / 32;
  int lane = threadIdx.x & 63;
  int wave = bid * 4 + (threadIdx.x >> 6);
  int r0 = wave * 16;
  if (r0 >= NN) return;
  int lrow = lane & 15, lgrp = lane >> 4;
  const unsigned short* ap = A + (size_t)(r0 + lrow) * K + lgrp * 8;
  f32x4 acc[4];
#pragma unroll
  for (int nt = 0; nt < 4; ++nt) acc[nt] = (f32x4){0.f, 0.f, 0.f, 0.f};
#pragma unroll
  for (int kt = 0; kt < KT; ++kt) {
    bf16x8 af = *reinterpret_cast<const bf16x8*>(ap + kt * 32);
#pragma unroll
    for (int nt = 0; nt < 4; ++nt) {
      bf16x8 bfr = *reinterpret_cast<const bf16x8*>(Bf + (size_t)((kt * 4 + nt) * 64 + lane) * 8);
      acc[nt] = __builtin_amdgcn_mfma_f32_16x16x32_bf16(af, bfr, acc[nt], 0, 0, 0);
    }
  }
#pragma unroll
  for (int nt = 0; nt < 4; ++nt) {
#pragma unroll
    for (int reg = 0; reg < 4; ++reg) {
      int rr = r0 + lgrp * 4 + reg;
      int cc = coff + nt * 16 + lrow;
      float v = acc[nt][reg];
      if (MODE != 1) v += bias[nt * 16 + lrow];
      if (MODE == 0) v = fmaxf(v, 0.f);
      if (MODE == 2) Cf[(size_t)rr * ldc + cc] = v;
      else           Cb[(size_t)rr * ldc + cc] = f2bf(v);
    }
  }
}

template<int K, int MODE>
__global__ __launch_bounds__(256) void k_mgemm(const unsigned short* __restrict__ A,
                                               const unsigned short* __restrict__ Bf,
                                               const float* __restrict__ bias,
                                               unsigned short* __restrict__ Cb,
                                               float* __restrict__ Cf,
                                               int ldc, int coff) {
  mgemm_body<K, MODE>(blockIdx.x, A, Bf, bias, Cb, Cf, ldc, coff);
}

// ---- fused: gather<96> + mgemm<96> ----
__global__ __launch_bounds__(256) void k_fuse(const unsigned short* __restrict__ hsrc,
                                              const float* __restrict__ dinv,
                                              const int* __restrict__ rowptr,
                                              const unsigned* __restrict__ rec,
                                              unsigned short* __restrict__ pout,
                                              const unsigned short* __restrict__ Bf,
                                              const float* __restrict__ bias,
                                              unsigned short* __restrict__ c1,
                                              int coff) {
  if (blockIdx.x < GH96)
    gather_body<96, 0>(blockIdx.x, hsrc, dinv, rowptr, rec, nullptr, pout, nullptr);
  else
    mgemm_body<96, 0>(blockIdx.x - GH96, hsrc, Bf, bias, c1, nullptr, 192, coff);
}

// ---- triple K=192 GEMM sharing A=c1: out(fp32,+bc) | z1(bf16) | z2(bf16) ----
__global__ __launch_bounds__(256) void k_mgemm3(const unsigned short* __restrict__ A,
                                                const unsigned short* __restrict__ BfWc,
                                                const float* __restrict__ bc,
                                                float* __restrict__ out,
                                                unsigned short* __restrict__ z1,
                                                unsigned short* __restrict__ z2) {
  constexpr int KT = 6;
  int lane = threadIdx.x & 63;
  int wave = blockIdx.x * 4 + (threadIdx.x >> 6);
  int r0 = wave * 16;
  if (r0 >= NN) return;
  int lrow = lane & 15, lgrp = lane >> 4;
  const unsigned short* ap = A + (size_t)(r0 + lrow) * 192 + lgrp * 8;
  const unsigned short* B0 = BfWc;
  const unsigned short* B1 = BfWc + (size_t)1536 * 8;
  const unsigned short* B2 = BfWc + (size_t)2 * 1536 * 8;
  f32x4 a0[4], a1[4], a2[4];
#pragma unroll
  for (int nt = 0; nt < 4; ++nt) {
    a0[nt] = (f32x4){0.f, 0.f, 0.f, 0.f};
    a1[nt] = (f32x4){0.f, 0.f, 0.f, 0.f};
    a2[nt] = (f32x4){0.f, 0.f, 0.f, 0.f};
  }
#pragma unroll
  for (int kt = 0; kt < KT; ++kt) {
    bf16x8 af = *reinterpret_cast<const bf16x8*>(ap + kt * 32);
#pragma unroll
    for (int nt = 0; nt < 4; ++nt) {
      size_t fo = (size_t)((kt * 4 + nt) * 64 + lane) * 8;
      bf16x8 b0 = *reinterpret_cast<const bf16x8*>(B0 + fo);
      bf16x8 b1 = *reinterpret_cast<const bf16x8*>(B1 + fo);
      bf16x8 b2 = *reinterpret_cast<const bf16x8*>(B2 + fo);
      a0[nt] = __builtin_amdgcn_mfma_f32_16x16x32_bf16(af, b0, a0[nt], 0, 0, 0);
      a1[nt] = __builtin_amdgcn_mfma_f32_16x16x32_bf16(af, b1, a1[nt], 0, 0, 0);
      a2[nt] = __builtin_amdgcn_mfma_f32_16x16x32_bf16(af, b2, a2[nt], 0, 0, 0);
    }
  }
#pragma unroll
  for (int nt = 0; nt < 4; ++nt) {
#pragma unroll
    for (int reg = 0; reg < 4; ++reg) {
      int rr = r0 + lgrp * 4 + reg;
      int cc = nt * 16 + lrow;
      out[(size_t)rr * 64 + cc] = a0[nt][reg] + bc[cc];
      z1[(size_t)rr * 64 + cc] = f2bf(a1[nt][reg]);
      z2[(size_t)rr * 64 + cc] = f2bf(a2[nt][reg]);
    }
  }
}

template<int MODE>
__global__ __launch_bounds__(256) void k_gather64(const unsigned short* __restrict__ h,
                                                  const float* __restrict__ dinv,
                                                  const int* __restrict__ rowptr,
                                                  const unsigned* __restrict__ rec,
                                                  const unsigned short* __restrict__ add,
                                                  unsigned short* __restrict__ outb,
                                                  float* __restrict__ outf) {
  gather_body<64, MODE>(blockIdx.x, h, dinv, rowptr, rec, add, outb, outf);
}

extern "C" void kernel_launch(void* const* d_in, const int* in_sizes, int n_in,
                              void* d_out, int out_size, void* d_ws, size_t ws_size,
                              hipStream_t stream) {
  const float* x    = (const float*)d_in[0];
  const int*   ei   = (const int*)d_in[1];
  const float* ew   = (const float*)d_in[2];
  const float* W1   = (const float*)d_in[3];
  const float* b1   = (const float*)d_in[4];
  const float* W2   = (const float*)d_in[5];
  const float* b2   = (const float*)d_in[6];
  const float* Wlin = (const float*)d_in[7];
  const float* bl   = (const float*)d_in[8];
  float* out = (float*)d_out;

  const int* row = ei;
  const int* col = ei + NE;

  char* wsb = (char*)d_ws;
  unsigned long long* packed8 = (unsigned long long*)wsb; wsb += (size_t)8 * NN * 8;
  float* dinv    = (float*)wsb;  wsb += NN * 4;
  int*   cnttot  = (int*)wsb;    wsb += NN * 4;
  int*   rowptr  = (int*)wsb;    wsb += (NN + 1) * 4;
  int*   partial = (int*)wsb;    wsb += 256 * 4;
  wsb = (char*)(((size_t)wsb + 15) & ~(size_t)15);
  unsigned short* cumoff = (unsigned short*)wsb; wsb += (size_t)NN * 8 * 2;
  unsigned short* posarr = (unsigned short*)wsb; wsb += NE * 2;
  wsb = (char*)(((size_t)wsb + 15) & ~(size_t)15);
  unsigned* rec  = (unsigned*)wsb; wsb += (size_t)NE * 4;
  float* Wc      = (float*)wsb;  wsb += 3 * 192 * 64 * 4;
  float* bc      = (float*)wsb;  wsb += 64 * 4;
  wsb = (char*)(((size_t)wsb + 15) & ~(size_t)15);
  unsigned short* BfW1 = (unsigned short*)wsb; wsb += (size_t)3 * 768 * 8 * 2;   // K=96 frags
  unsigned short* BfWc = (unsigned short*)wsb; wsb += (size_t)3 * 1536 * 8 * 2;  // K=192 frags
  wsb = (char*)(((size_t)wsb + 15) & ~(size_t)15);
  unsigned short* xb   = (unsigned short*)wsb; wsb += (size_t)NN * 96 * 2;
  unsigned short* c1   = (unsigned short*)wsb; wsb += (size_t)NN * 192 * 2;
  unsigned short* bufB = (unsigned short*)wsb;  // p1|p2 (2*96) then z1|z2|sB (3*64)
  unsigned short* p1 = bufB;
  unsigned short* p2 = bufB + (size_t)NN * 96;
  unsigned short* z1 = bufB;
  unsigned short* z2 = bufB + (size_t)NN * 64;
  unsigned short* sB = bufB + (size_t)NN * 128;

  // zero privatized histograms (own kernel; runtime fill was 40 us)
  k_zero<<<ZB, 256, 0, stream>>>((uint4*)packed8);
  // mega-start: histogram atomics + weight prep + cast, one launch
  const int CASTB = (NN * 24 + 255) / 256;
  k_start<<<FB + 144 + 1 + 9 + CASTB, 256, 0, stream>>>(x, W1, W2, Wlin, b2, bl,
                                                        col, ew, packed8, posarr,
                                                        Wc, bc, BfW1, xb);
  // dinv + rowptr
  k_scan_part<<<NB, 256, 0, stream>>>(packed8, partial, dinv, cnttot, cumoff);
  k_scan_final<<<NB, 256, 0, stream>>>(cnttot, partial, rowptr);
  // atomic-free CSR fill (4B records) + BfWc pack
  k_fill<<<FB + 18, 256, 0, stream>>>(row, col, ew, dinv, rowptr, posarr, cumoff, rec, Wc, BfWc);

  // conv1 (fused gather+GEMM): c1 = relu([x@W1_0 | (Ax)@W1_1 | (A^2x)@W1_2] + b1)
  k_fuse<<<GH96 + GG, 256, 0, stream>>>(xb, dinv, rowptr, rec, p1, BfW1, b1, c1, 0);
  k_fuse<<<GH96 + GG, 256, 0, stream>>>(p1, dinv, rowptr, rec, p2,
                                        BfW1 + (size_t)768 * 8, b1 + 64, c1, 64);
  k_mgemm<96, 0><<<GG, 256, 0, stream>>>(p2, BfW1 + (size_t)2 * 768 * 8, b1 + 128,
                                         c1, nullptr, 192, 128);

  // conv2 + final linear (re-associated): out = c1@Wc0 + bc + A(z1 + A z2)
  k_mgemm3<<<GG, 256, 0, stream>>>(c1, BfWc, bc, out, z1, z2);
  k_gather64<1><<<GH64, 256, 0, stream>>>(z2, dinv, rowptr, rec, z1, sB, nullptr);
  k_gather64<2><<<GH64, 256, 0, stream>>>(sB, dinv, rowptr, rec, nullptr, nullptr, out);
}

// Round 10
// 209.381 us; speedup vs baseline: 1.7545x; 1.0072x over previous
//
#include <hip/hip_runtime.h>

static constexpr int NN = 50000;
static constexpr int NE = 800000;
static constexpr int NB = (NN + 255) / 256;   // 196
static constexpr int FB = (NE + 255) / 256;   // 3125 edge blocks
static constexpr int GG = ((NN + 15) / 16 + 3) / 4;  // 782 mgemm blocks (4 waves x 16 rows)
static constexpr int G128 = (NN * 16 + 255) / 256;   // 3125 gather<128> blocks
static constexpr int G64  = (NN * 8 + 255) / 256;    // 1563 gather<64> blocks
static constexpr int ZB = (NN * 8 * 8 / 16 + 255) / 256;  // 782 zero blocks
static constexpr float DSCALE = 33554432.f;   // 2^25 fixed-point for degree

typedef __attribute__((ext_vector_type(8))) short bf16x8;
typedef __attribute__((ext_vector_type(4))) float f32x4;

__device__ __forceinline__ unsigned short f2bf(float f) {  // RNE
  unsigned u = __float_as_uint(f);
  u += 0x7fffu + ((u >> 16) & 1u);
  return (unsigned short)(u >> 16);
}
__device__ __forceinline__ float bf_lo(unsigned v) { return __uint_as_float(v << 16); }
__device__ __forceinline__ float bf_hi(unsigned v) { return __uint_as_float(v & 0xffff0000u); }

__device__ __forceinline__ void bf8_unpack(uint4 v, float* f) {
  f[0] = bf_lo(v.x); f[1] = bf_hi(v.x); f[2] = bf_lo(v.y); f[3] = bf_hi(v.y);
  f[4] = bf_lo(v.z); f[5] = bf_hi(v.z); f[6] = bf_lo(v.w); f[7] = bf_hi(v.w);
}
__device__ __forceinline__ uint4 bf8_pack(const float* f) {
  uint4 o;
  o.x = (unsigned)f2bf(f[0]) | ((unsigned)f2bf(f[1]) << 16);
  o.y = (unsigned)f2bf(f[2]) | ((unsigned)f2bf(f[3]) << 16);
  o.z = (unsigned)f2bf(f[4]) | ((unsigned)f2bf(f[5]) << 16);
  o.w = (unsigned)f2bf(f[6]) | ((unsigned)f2bf(f[7]) << 16);
  return o;
}
__device__ __forceinline__ unsigned short f2h(float f) {
  _Float16 h = (_Float16)f;
  unsigned short u; __builtin_memcpy(&u, &h, 2);
  return u;
}
__device__ __forceinline__ float h2f(unsigned short u) {
  _Float16 h; __builtin_memcpy(&h, &u, 2);
  return (float)h;
}

// ---- zero the privatized histograms ----
__global__ __launch_bounds__(256) void k_zero(uint4* __restrict__ p) {
  int i = blockIdx.x * 256 + threadIdx.x;
  if (i < NN * 8 * 8 / 16) p[i] = make_uint4(0u, 0u, 0u, 0u);
}

// ---- B-fragment packing (16x16x32 MFMA B layout) ----
__device__ __forceinline__ void bfrag_item(const float* __restrict__ W,
                                           unsigned short* __restrict__ Bf,
                                           int K, int idx) {
  int fragc = (K / 32) * 4 * 64;
  int mat = idx / fragc;
  int rem = idx - mat * fragc;
  int lane = rem & 63;
  int nt = (rem >> 6) & 3;
  int kt = rem >> 8;
  int lrow = lane & 15, lgrp = lane >> 4;
  const float* Wm = W + (size_t)mat * K * 64;
  float o[8];
#pragma unroll
  for (int j = 0; j < 8; ++j)
    o[j] = Wm[(size_t)(kt * 32 + lgrp * 8 + j) * 64 + nt * 16 + lrow];
  *reinterpret_cast<uint4*>(Bf + (size_t)idx * 8) = bf8_pack(o);
}

// ---- mega-start: deg_hist | Wc | bc | BfW1 | cast x->xb  (grid-split) ----
__global__ __launch_bounds__(256) void k_start(const float* __restrict__ x,
                                               const float* __restrict__ W1,
                                               const float* __restrict__ W2,
                                               const float* __restrict__ Wlin,
                                               const float* __restrict__ b2,
                                               const float* __restrict__ bl,
                                               const int* __restrict__ col,
                                               const float* __restrict__ ew,
                                               unsigned long long* __restrict__ packed8,
                                               unsigned short* __restrict__ posarr,
                                               float* __restrict__ Wc,
                                               float* __restrict__ bc,
                                               unsigned short* __restrict__ BfW1,
                                               unsigned short* __restrict__ xb) {
  int b = blockIdx.x, t = threadIdx.x;
  if (b < FB) {  // per-edge histogram: XCD-privatized 64-bit atomic; old low = position
    int e = b * 256 + t;
    if (e < NE) {
      unsigned fx = (unsigned)(ew[e] * DSCALE + 0.5f);
      int k = b & 7;
      unsigned long long old =
          atomicAdd(&packed8[(size_t)k * NN + col[e]], (((unsigned long long)fx) << 32) | 1ull);
      __builtin_nontemporal_store((unsigned short)(old & 0xffffull), posarr + e);
    }
    return;
  }
  b -= FB;
  if (b < 144) {  // Wc[p] = W2[p] @ Wl[64p:64p+64,:]
    int idx = b * 256 + t;
    int j = idx & 63;
    int k = (idx >> 6) % 192;
    int p = idx / (192 * 64);
    float s = 0.f;
    for (int m = 0; m < 64; ++m)
      s += W2[(p * 192 + k) * 64 + m] * Wlin[(p * 64 + m) * 64 + j];
    Wc[idx] = s;
    return;
  }
  b -= 144;
  if (b == 0) {  // bc
    if (t < 64) {
      float s = bl[t];
      for (int p = 0; p < 3; ++p)
        for (int m = 0; m < 64; ++m)
          s += b2[p * 64 + m] * Wlin[(p * 64 + m) * 64 + t];
      bc[t] = s;
    }
    return;
  }
  b -= 1;
  if (b < 9) {  // BfW1: 3 mats * 768 frags
    int idx = b * 256 + t;
    if (idx < 3 * 768) bfrag_item(W1, BfW1, 96, idx);
    return;
  }
  b -= 9;
  {  // cast x -> xb (float4 groups), non-temporal store to spare L2 for atomics
    int i = b * 256 + t;
    if (i < NN * 24) {
      float4 v = reinterpret_cast<const float4*>(x)[i];
      unsigned lo = (unsigned)f2bf(v.x) | ((unsigned)f2bf(v.y) << 16);
      unsigned hi = (unsigned)f2bf(v.z) | ((unsigned)f2bf(v.w) << 16);
      unsigned long long pk = (unsigned long long)lo | ((unsigned long long)hi << 32);
      __builtin_nontemporal_store(pk, reinterpret_cast<unsigned long long*>(xb) + i);
    }
  }
}

// ---- scan part: sum 8 copies -> cnttot, dinv, per-copy offsets; block partial ----
__global__ __launch_bounds__(256) void k_scan_part(const unsigned long long* __restrict__ packed8,
                                                   int* __restrict__ partial,
                                                   float* __restrict__ dinv,
                                                   int* __restrict__ cnttot,
                                                   unsigned short* __restrict__ cumoff) {
  __shared__ int s[256];
  int t = threadIdx.x;
  int i = blockIdx.x * 256 + t;
  int total = 0;
  if (i < NN) {
    unsigned long long wsum = 0;
    int run = 0;
    unsigned short co[8];
#pragma unroll
    for (int k = 0; k < 8; ++k) {
      unsigned long long pk = packed8[(size_t)k * NN + i];
      co[k] = (unsigned short)run;
      run += (int)(pk & 0xffffffffu);
      wsum += (pk >> 32);
    }
    total = run;
    dinv[i] = rsqrtf(1.0f + (float)wsum * (1.0f / DSCALE));  // +1 self-loop
    cnttot[i] = total;
    uint4 pk4;
    pk4.x = (unsigned)co[0] | ((unsigned)co[1] << 16);
    pk4.y = (unsigned)co[2] | ((unsigned)co[3] << 16);
    pk4.z = (unsigned)co[4] | ((unsigned)co[5] << 16);
    pk4.w = (unsigned)co[6] | ((unsigned)co[7] << 16);
    reinterpret_cast<uint4*>(cumoff)[i] = pk4;
  }
  s[t] = total;
  __syncthreads();
  for (int off = 128; off > 0; off >>= 1) {
    if (t < off) s[t] += s[t + off];
    __syncthreads();
  }
  if (t == 0) partial[blockIdx.x] = s[0];
}

// ---- scan final: in-block base over partials + local scan -> rowptr ----
__global__ __launch_bounds__(256) void k_scan_final(const int* __restrict__ cnttot,
                                                    const int* __restrict__ partial,
                                                    int* __restrict__ rowptr) {
  __shared__ int s[256], p[256];
  int t = threadIdx.x;
  p[t] = (t < NB) ? partial[t] : 0;
  __syncthreads();
#pragma unroll
  for (int off = 1; off < 256; off <<= 1) {
    int a = (t >= off) ? p[t - off] : 0;
    __syncthreads();
    p[t] += a;
    __syncthreads();
  }
  int base = (blockIdx.x > 0) ? p[blockIdx.x - 1] : 0;
  int i = blockIdx.x * 256 + t;
  int v = (i < NN) ? cnttot[i] : 0;
  s[t] = v;
  __syncthreads();
#pragma unroll
  for (int off = 1; off < 256; off <<= 1) {
    int a = (t >= off) ? s[t - off] : 0;
    __syncthreads();
    s[t] += a;
    __syncthreads();
  }
  if (i < NN) rowptr[i] = s[t] - v + base;
  if (blockIdx.x == 0 && t == 0) rowptr[NN] = NE;
}

// ---- conv1 GEMM body: K=96, 3 mats: c1_0=relu(x@W1_0+b1_0) | y=[x@W1_1 | x@W1_2] ----
__device__ __forceinline__ void mgemm_c1_body(int bid,
                                              const unsigned short* __restrict__ A,
                                              const unsigned short* __restrict__ BfW1,
                                              const float* __restrict__ b1,
                                              unsigned short* __restrict__ c1,
                                              unsigned short* __restrict__ y) {
  constexpr int KT = 3;
  int lane = threadIdx.x & 63;
  int wave = bid * 4 + (threadIdx.x >> 6);
  int r0 = wave * 16;
  if (r0 >= NN) return;
  int lrow = lane & 15, lgrp = lane >> 4;
  const unsigned short* ap = A + (size_t)(r0 + lrow) * 96 + lgrp * 8;
  const unsigned short* B0 = BfW1;
  const unsigned short* B1 = BfW1 + (size_t)768 * 8;
  const unsigned short* B2 = BfW1 + (size_t)2 * 768 * 8;
  f32x4 a0[4], a1[4], a2[4];
#pragma unroll
  for (int nt = 0; nt < 4; ++nt) {
    a0[nt] = (f32x4){0.f, 0.f, 0.f, 0.f};
    a1[nt] = (f32x4){0.f, 0.f, 0.f, 0.f};
    a2[nt] = (f32x4){0.f, 0.f, 0.f, 0.f};
  }
#pragma unroll
  for (int kt = 0; kt < KT; ++kt) {
    bf16x8 af = *reinterpret_cast<const bf16x8*>(ap + kt * 32);
#pragma unroll
    for (int nt = 0; nt < 4; ++nt) {
      size_t fo = (size_t)((kt * 4 + nt) * 64 + lane) * 8;
      bf16x8 b0 = *reinterpret_cast<const bf16x8*>(B0 + fo);
      bf16x8 b1f = *reinterpret_cast<const bf16x8*>(B1 + fo);
      bf16x8 b2f = *reinterpret_cast<const bf16x8*>(B2 + fo);
      a0[nt] = __builtin_amdgcn_mfma_f32_16x16x32_bf16(af, b0, a0[nt], 0, 0, 0);
      a1[nt] = __builtin_amdgcn_mfma_f32_16x16x32_bf16(af, b1f, a1[nt], 0, 0, 0);
      a2[nt] = __builtin_amdgcn_mfma_f32_16x16x32_bf16(af, b2f, a2[nt], 0, 0, 0);
    }
  }
#pragma unroll
  for (int nt = 0; nt < 4; ++nt) {
#pragma unroll
    for (int reg = 0; reg < 4; ++reg) {
      int rr = r0 + lgrp * 4 + reg;
      int cc = nt * 16 + lrow;
      c1[(size_t)rr * 192 + cc] = f2bf(fmaxf(a0[nt][reg] + b1[cc], 0.f));
      y[(size_t)rr * 128 + cc]      = f2bf(a1[nt][reg]);
      y[(size_t)rr * 128 + 64 + cc] = f2bf(a2[nt][reg]);
    }
  }
}

// ---- fill CSR (no atomics) + bfrag(Wc) + conv1 GEMM, grid-split ----
__global__ __launch_bounds__(256) void k_fill3(const int* __restrict__ row,
                                               const int* __restrict__ col,
                                               const float* __restrict__ w,
                                               const float* __restrict__ dinv,
                                               const int* __restrict__ rowptr,
                                               const unsigned short* __restrict__ posarr,
                                               const unsigned short* __restrict__ cumoff,
                                               unsigned* __restrict__ rec,
                                               const float* __restrict__ Wc,
                                               unsigned short* __restrict__ BfWc,
                                               const unsigned short* __restrict__ xb,
                                               const unsigned short* __restrict__ BfW1,
                                               const float* __restrict__ b1,
                                               unsigned short* __restrict__ c1,
                                               unsigned short* __restrict__ y) {
  int b = blockIdx.x;
  if (b < FB) {
    int e = b * 256 + threadIdx.x;
    if (e < NE) {
      int r = row[e], c = col[e];
      int k = b & 7;
      int pos = rowptr[c] + (int)cumoff[c * 8 + k] + (int)posarr[e];
      float nrm = dinv[r] * w[e] * dinv[c];
      rec[pos] = (unsigned)r | ((unsigned)f2h(nrm) << 16);
    }
    return;
  }
  b -= FB;
  if (b < 18) {
    int idx = b * 256 + threadIdx.x;
    if (idx < 3 * 1536) bfrag_item(Wc, BfWc, 192, idx);
    return;
  }
  mgemm_c1_body(b - 18, xb, BfW1, b1, c1, y);
}

// ---- propagate body (bf16 h, fp32 accum, fp16 nrm, unroll-4).
// MODE 1: outb = bf16(add + prop)                       (sB = z1 + A z2)
// MODE 2: outf += prop                                  (out += A sB)
// MODE 3: F=128 split: cols 0-63 -> relu(+bias)->c1[64..127]; cols 64-127 -> outb (q2)
// MODE 4: F=64: relu(+bias) -> c1[128..191]
template<int F, int MODE>
__device__ __forceinline__ void gather_body(int bid,
                                            const unsigned short* __restrict__ h,
                                            const float* __restrict__ dinv,
                                            const int* __restrict__ rowptr,
                                            const unsigned* __restrict__ rec,
                                            const unsigned short* __restrict__ add,
                                            unsigned short* __restrict__ outb,
                                            float* __restrict__ outf,
                                            const float* __restrict__ bias,
                                            unsigned short* __restrict__ c1) {
  constexpr int CH = F / 8;
  int idx = bid * 256 + threadIdx.x;
  if (idx >= NN * CH) return;
  int node = idx / CH;
  int col = (idx - node * CH) * 8;
  const size_t base = (size_t)node * F + col;
  uint4 hv = *reinterpret_cast<const uint4*>(h + base);
  float hx[8]; bf8_unpack(hv, hx);
  float d2 = dinv[node]; d2 *= d2;
  float a[8];
#pragma unroll
  for (int j = 0; j < 8; ++j) a[j] = d2 * hx[j];
  if (MODE == 1) {
    uint4 av = *reinterpret_cast<const uint4*>(add + base);
    float ax[8]; bf8_unpack(av, ax);
#pragma unroll
    for (int j = 0; j < 8; ++j) a[j] += ax[j];
  } else if (MODE == 2) {
    float4 o0 = *reinterpret_cast<const float4*>(outf + base);
    float4 o1 = *reinterpret_cast<const float4*>(outf + base + 4);
    a[0] += o0.x; a[1] += o0.y; a[2] += o0.z; a[3] += o0.w;
    a[4] += o1.x; a[5] += o1.y; a[6] += o1.z; a[7] += o1.w;
  }
  int e = rowptr[node], e1 = rowptr[node + 1];
  for (; e + 4 <= e1; e += 4) {
    unsigned rv0 = rec[e], rv1 = rec[e + 1], rv2 = rec[e + 2], rv3 = rec[e + 3];
    uint4 s0 = *reinterpret_cast<const uint4*>(h + (size_t)(rv0 & 0xffffu) * F + col);
    uint4 s1 = *reinterpret_cast<const uint4*>(h + (size_t)(rv1 & 0xffffu) * F + col);
    uint4 s2 = *reinterpret_cast<const uint4*>(h + (size_t)(rv2 & 0xffffu) * F + col);
    uint4 s3 = *reinterpret_cast<const uint4*>(h + (size_t)(rv3 & 0xffffu) * F + col);
    float nm0 = h2f((unsigned short)(rv0 >> 16));
    float nm1 = h2f((unsigned short)(rv1 >> 16));
    float nm2 = h2f((unsigned short)(rv2 >> 16));
    float nm3 = h2f((unsigned short)(rv3 >> 16));
    float sx[8];
    bf8_unpack(s0, sx);
#pragma unroll
    for (int j = 0; j < 8; ++j) a[j] += nm0 * sx[j];
    bf8_unpack(s1, sx);
#pragma unroll
    for (int j = 0; j < 8; ++j) a[j] += nm1 * sx[j];
    bf8_unpack(s2, sx);
#pragma unroll
    for (int j = 0; j < 8; ++j) a[j] += nm2 * sx[j];
    bf8_unpack(s3, sx);
#pragma unroll
    for (int j = 0; j < 8; ++j) a[j] += nm3 * sx[j];
  }
  for (; e < e1; ++e) {
    unsigned rv = rec[e];
    uint4 sv = *reinterpret_cast<const uint4*>(h + (size_t)(rv & 0xffffu) * F + col);
    float nm = h2f((unsigned short)(rv >> 16));
    float sx[8]; bf8_unpack(sv, sx);
#pragma unroll
    for (int j = 0; j < 8; ++j) a[j] += nm * sx[j];
  }
  if (MODE == 1) {
    *reinterpret_cast<uint4*>(outb + base) = bf8_pack(a);
  } else if (MODE == 2) {
    *reinterpret_cast<float4*>(outf + base) = make_float4(a[0], a[1], a[2], a[3]);
    *reinterpret_cast<float4*>(outf + base + 4) = make_float4(a[4], a[5], a[6], a[7]);
  } else if (MODE == 3) {
    if (col < 64) {
      float4 b0 = *reinterpret_cast<const float4*>(bias + col);
      float4 b1v = *reinterpret_cast<const float4*>(bias + col + 4);
      a[0] = fmaxf(a[0] + b0.x, 0.f); a[1] = fmaxf(a[1] + b0.y, 0.f);
      a[2] = fmaxf(a[2] + b0.z, 0.f); a[3] = fmaxf(a[3] + b0.w, 0.f);
      a[4] = fmaxf(a[4] + b1v.x, 0.f); a[5] = fmaxf(a[5] + b1v.y, 0.f);
      a[6] = fmaxf(a[6] + b1v.z, 0.f); a[7] = fmaxf(a[7] + b1v.w, 0.f);
      *reinterpret_cast<uint4*>(c1 + (size_t)node * 192 + 64 + col) = bf8_pack(a);
    } else {
      *reinterpret_cast<uint4*>(outb + (size_t)node * 64 + (col - 64)) = bf8_pack(a);
    }
  } else {  // MODE 4
    float4 b0 = *reinterpret_cast<const float4*>(bias + col);
    float4 b1v = *reinterpret_cast<const float4*>(bias + col + 4);
    a[0] = fmaxf(a[0] + b0.x, 0.f); a[1] = fmaxf(a[1] + b0.y, 0.f);
    a[2] = fmaxf(a[2] + b0.z, 0.f); a[3] = fmaxf(a[3] + b0.w, 0.f);
    a[4] = fmaxf(a[4] + b1v.x, 0.f); a[5] = fmaxf(a[5] + b1v.y, 0.f);
    a[6] = fmaxf(a[6] + b1v.z, 0.f); a[7] = fmaxf(a[7] + b1v.w, 0.f);
    *reinterpret_cast<uint4*>(c1 + (size_t)node * 192 + 128 + col) = bf8_pack(a);
  }
}

template<int F, int MODE>
__global__ __launch_bounds__(256) void k_gather(const unsigned short* __restrict__ h,
                                                const float* __restrict__ dinv,
                                                const int* __restrict__ rowptr,
                                                const unsigned* __restrict__ rec,
                                                const unsigned short* __restrict__ add,
                                                unsigned short* __restrict__ outb,
                                                float* __restrict__ outf,
                                                const float* __restrict__ bias,
                                                unsigned short* __restrict__ c1) {
  gather_body<F, MODE>(blockIdx.x, h, dinv, rowptr, rec, add, outb, outf, bias, c1);
}

// ---- triple K=192 GEMM sharing A=c1: out(fp32,+bc) | z1(bf16) | z2(bf16) ----
__global__ __launch_bounds__(256) void k_mgemm3(const unsigned short* __restrict__ A,
                                                const unsigned short* __restrict__ BfWc,
                                                const float* __restrict__ bc,
                                                float* __restrict__ out,
                                                unsigned short* __restrict__ z1,
                                                unsigned short* __restrict__ z2) {
  constexpr int KT = 6;
  int lane = threadIdx.x & 63;
  int wave = blockIdx.x * 4 + (threadIdx.x >> 6);
  int r0 = wave * 16;
  if (r0 >= NN) return;
  int lrow = lane & 15, lgrp = lane >> 4;
  const unsigned short* ap = A + (size_t)(r0 + lrow) * 192 + lgrp * 8;
  const unsigned short* B0 = BfWc;
  const unsigned short* B1 = BfWc + (size_t)1536 * 8;
  const unsigned short* B2 = BfWc + (size_t)2 * 1536 * 8;
  f32x4 a0[4], a1[4], a2[4];
#pragma unroll
  for (int nt = 0; nt < 4; ++nt) {
    a0[nt] = (f32x4){0.f, 0.f, 0.f, 0.f};
    a1[nt] = (f32x4){0.f, 0.f, 0.f, 0.f};
    a2[nt] = (f32x4){0.f, 0.f, 0.f, 0.f};
  }
#pragma unroll
  for (int kt = 0; kt < KT; ++kt) {
    bf16x8 af = *reinterpret_cast<const bf16x8*>(ap + kt * 32);
#pragma unroll
    for (int nt = 0; nt < 4; ++nt) {
      size_t fo = (size_t)((kt * 4 + nt) * 64 + lane) * 8;
      bf16x8 b0 = *reinterpret_cast<const bf16x8*>(B0 + fo);
      bf16x8 b1 = *reinterpret_cast<const bf16x8*>(B1 + fo);
      bf16x8 b2 = *reinterpret_cast<const bf16x8*>(B2 + fo);
      a0[nt] = __builtin_amdgcn_mfma_f32_16x16x32_bf16(af, b0, a0[nt], 0, 0, 0);
      a1[nt] = __builtin_amdgcn_mfma_f32_16x16x32_bf16(af, b1, a1[nt], 0, 0, 0);
      a2[nt] = __builtin_amdgcn_mfma_f32_16x16x32_bf16(af, b2, a2[nt], 0, 0, 0);
    }
  }
#pragma unroll
  for (int nt = 0; nt < 4; ++nt) {
#pragma unroll
    for (int reg = 0; reg < 4; ++reg) {
      int rr = r0 + lgrp * 4 + reg;
      int cc = nt * 16 + lrow;
      out[(size_t)rr * 64 + cc] = a0[nt][reg] + bc[cc];
      z1[(size_t)rr * 64 + cc] = f2bf(a1[nt][reg]);
      z2[(size_t)rr * 64 + cc] = f2bf(a2[nt][reg]);
    }
  }
}

extern "C" void kernel_launch(void* const* d_in, const int* in_sizes, int n_in,
                              void* d_out, int out_size, void* d_ws, size_t ws_size,
                              hipStream_t stream) {
  const float* x    = (const float*)d_in[0];
  const int*   ei   = (const int*)d_in[1];
  const float* ew   = (const float*)d_in[2];
  const float* W1   = (const float*)d_in[3];
  const float* b1   = (const float*)d_in[4];
  const float* W2   = (const float*)d_in[5];
  const float* b2   = (const float*)d_in[6];
  const float* Wlin = (const float*)d_in[7];
  const float* bl   = (const float*)d_in[8];
  float* out = (float*)d_out;

  const int* row = ei;
  const int* col = ei + NE;

  char* wsb = (char*)d_ws;
  unsigned long long* packed8 = (unsigned long long*)wsb; wsb += (size_t)8 * NN * 8;
  float* dinv    = (float*)wsb;  wsb += NN * 4;
  int*   cnttot  = (int*)wsb;    wsb += NN * 4;
  int*   rowptr  = (int*)wsb;    wsb += (NN + 1) * 4;
  int*   partial = (int*)wsb;    wsb += 256 * 4;
  wsb = (char*)(((size_t)wsb + 15) & ~(size_t)15);
  unsigned short* cumoff = (unsigned short*)wsb; wsb += (size_t)NN * 8 * 2;
  unsigned short* posarr = (unsigned short*)wsb; wsb += NE * 2;
  wsb = (char*)(((size_t)wsb + 15) & ~(size_t)15);
  unsigned* rec  = (unsigned*)wsb; wsb += (size_t)NE * 4;
  float* Wc      = (float*)wsb;  wsb += 3 * 192 * 64 * 4;
  float* bc      = (float*)wsb;  wsb += 64 * 4;
  wsb = (char*)(((size_t)wsb + 15) & ~(size_t)15);
  unsigned short* BfW1 = (unsigned short*)wsb; wsb += (size_t)3 * 768 * 8 * 2;   // K=96 frags
  unsigned short* BfWc = (unsigned short*)wsb; wsb += (size_t)3 * 1536 * 8 * 2;  // K=192 frags
  wsb = (char*)(((size_t)wsb + 15) & ~(size_t)15);
  unsigned short* xb   = (unsigned short*)wsb; wsb += (size_t)NN * 96 * 2;
  unsigned short* c1   = (unsigned short*)wsb; wsb += (size_t)NN * 192 * 2;
  unsigned short* bufB = (unsigned short*)wsb;  // y(128)|q2(64), then z1|z2|sB (3*64)
  unsigned short* y  = bufB;                          // [N,128]
  unsigned short* q2 = bufB + (size_t)NN * 128;       // [N,64]
  unsigned short* z1 = bufB;                          // [N,64]
  unsigned short* z2 = bufB + (size_t)NN * 64;        // [N,64]
  unsigned short* sB = bufB + (size_t)NN * 128;       // [N,64]

  // zero privatized histograms
  k_zero<<<ZB, 256, 0, stream>>>((uint4*)packed8);
  // mega-start: histogram atomics + weight prep + cast, one launch
  const int CASTB = (NN * 24 + 255) / 256;
  k_start<<<FB + 144 + 1 + 9 + CASTB, 256, 0, stream>>>(x, W1, W2, Wlin, b2, bl,
                                                        col, ew, packed8, posarr,
                                                        Wc, bc, BfW1, xb);
  // dinv + rowptr
  k_scan_part<<<NB, 256, 0, stream>>>(packed8, partial, dinv, cnttot, cumoff);
  k_scan_final<<<NB, 256, 0, stream>>>(cnttot, partial, rowptr);
  // CSR fill + BfWc pack + conv1 GEMM (c1_0 relu, y = x@[W1_1|W1_2]) co-launched
  k_fill3<<<FB + 18 + GG, 256, 0, stream>>>(row, col, ew, dinv, rowptr, posarr, cumoff,
                                            rec, Wc, BfWc, xb, BfW1, b1, c1, y);

  // conv1 propagation (projection-first): q = A y -> c1_1 (bias+relu) | q2; t = A q2 -> c1_2
  k_gather<128, 3><<<G128, 256, 0, stream>>>(y, dinv, rowptr, rec, nullptr, q2, nullptr,
                                             b1 + 64, c1);
  k_gather<64, 4><<<G64, 256, 0, stream>>>(q2, dinv, rowptr, rec, nullptr, nullptr, nullptr,
                                           b1 + 128, c1);

  // conv2 + final linear (re-associated): out = c1@Wc0 + bc + A(z1 + A z2)
  k_mgemm3<<<GG, 256, 0, stream>>>(c1, BfWc, bc, out, z1, z2);
  k_gather<64, 1><<<G64, 256, 0, stream>>>(z2, dinv, rowptr, rec, z1, sB, nullptr,
                                           nullptr, nullptr);
  k_gather<64, 2><<<G64, 256, 0, stream>>>(sB, dinv, rowptr, rec, nullptr, nullptr, out,
                                           nullptr, nullptr);
}